// Round 15
// baseline (449.272 us; speedup 1.0000x reference)
//
#include <hip/hip_runtime.h>
#include <math.h>

#define N_TOK 131072
#define VOCAB 50257
#define DIM   512
#define K_CON 512
#define NPARTS 12565   // ceil(VOCAB/4)

// d_out layout (float32 elements)
#define OFF_ENC  ((size_t)0)
#define OFF_QW   ((size_t)67108864)
#define OFF_DOCU ((size_t)134217728)
#define OFF_OUT  ((size_t)134218240)
#define OFF_VQ   ((size_t)134268497)
#define OFF_LTS  ((size_t)134268498)

// ws layout (bytes)
#define WS_COUNTS 0        // 512 * u32
#define WS_VQ     2048     // double
#define WS_LTS    2056     // double
#define WS_SUMV   2072     // double
#define WS_NFLAG  2080     // u32
#define WS_NARR   4096     // 512 f32
#define WS_SARR   6144     // 512 f32
#define WS_BINC   8192     // VOCAB u32
#define WS_LOGITS 209920   // VOCAB f32 (holds exp(logit))
#define WS_FLAGS  411648   // FLAG_CAP u32  (ends 542720)
#define WS_PART   544768   // NPARTS double (ends 645288)
#define FLAG_CAP  32768

typedef __attribute__((ext_vector_type(4)))  float f32x4;
typedef __attribute__((ext_vector_type(8)))  _Float16 f16x8;
typedef __attribute__((ext_vector_type(16))) float f32x16;

// Codebook as fp16 of (512*c): frag [(s*2+hf)*512 + c] x f16x8. 512 KB.
// K-step tile s = 16 KB at byte offset s*16384 (first 8 KB hf=0, then hf=1).
__device__ _Float16 g_B1[32 * 2 * 512 * 8];
// Embedding table as fp16 (unscaled), row-major [VOCAB][512]. ~51.5 MB.
__device__ _Float16 g_A16[(size_t)VOCAB * DIM];
// Per-vocab-row |x|^2 (double-accumulated, rounded to f32).
__device__ float g_NW[VOCAB];

__device__ inline void gload16(const void* g, void* l) {
    __builtin_amdgcn_global_load_lds(
        (const __attribute__((address_space(1))) unsigned int*)g,
        (__attribute__((address_space(3))) unsigned int*)l, 16, 0, 0);
}

// ---------------------------------------------------------------------------
// merged: n/s arrays + codebook fp16 (512*c) prep + ws scalar zeroing
__global__ void k_nsprep(const float* __restrict__ cw, float* __restrict__ n_arr,
                         float* __restrict__ s_arr, _Float16* __restrict__ b1,
                         uint4* __restrict__ wz) {
    if (blockIdx.x == 0) {
        uint4 z; z.x = 0u; z.y = 0u; z.z = 0u; z.w = 0u;
        wz[threadIdx.x] = z;          // 256 * 16 B = 4 KB scalar region
    }
    int w = threadIdx.x >> 6, lane = threadIdx.x & 63;
    int r = blockIdx.x * 4 + w;
    const float* row = cw + (size_t)r * DIM;
    {
        float4 a = *(const float4*)(row + lane * 8);
        float4 b = *(const float4*)(row + lane * 8 + 4);
        float v[8] = {a.x,a.y,a.z,a.w,b.x,b.y,b.z,b.w};
        double na = 0.0, sa = 0.0;
        #pragma unroll
        for (int e = 0; e < 8; ++e) { na += (double)v[e]*v[e]; sa += (double)v[e]; }
        for (int off = 32; off; off >>= 1) {
            na += __shfl_down(na, off);
            sa += __shfl_down(sa, off);
        }
        if (lane == 0) { n_arr[r] = (float)na; s_arr[r] = (float)sa; }
    }
    {
        int s = lane >> 1, hf = lane & 1;
        const float* p = row + s * 16 + hf * 8;
        float4 xa = *(const float4*)p;
        float4 xb = *(const float4*)(p + 4);
        float xf[8] = {xa.x,xa.y,xa.z,xa.w,xb.x,xb.y,xb.z,xb.w};
        f16x8 h8;
        #pragma unroll
        for (int e = 0; e < 8; ++e) h8[e] = (_Float16)(xf[e] * 512.0f);
        *(f16x8*)&b1[(((size_t)s * 2 + hf) * 512 + r) * 8] = h8;
    }
}

// ---------------------------------------------------------------------------
// emb -> fp16 table + per-row |x|^2 + binc zeroing (covers all VOCAB rows)
__global__ void k_prepa(const float* __restrict__ emb, _Float16* __restrict__ a16,
                        float* __restrict__ nw, unsigned* __restrict__ binc) {
    int wv = threadIdx.x >> 6, lane = threadIdx.x & 63;
    int r = blockIdx.x * 4 + wv;
    if (r >= VOCAB) return;
    const float* row = emb + (size_t)r * DIM;
    float4 a = *(const float4*)(row + lane * 8);
    float4 b = *(const float4*)(row + lane * 8 + 4);
    float v[8] = {a.x,a.y,a.z,a.w,b.x,b.y,b.z,b.w};
    f16x8 h;
    double na = 0.0;
    #pragma unroll
    for (int e = 0; e < 8; ++e) { h[e] = (_Float16)v[e]; na += (double)v[e]*v[e]; }
    *(f16x8*)&a16[(size_t)r * DIM + lane * 8] = h;
    for (int off = 32; off; off >>= 1) na += __shfl_down(na, off);
    if (lane == 0) { nw[r] = (float)na; binc[r] = 0u; }
}

// ---------------------------------------------------------------------------
// Main: fp16 single-term MFMA distance GEMM, BM=128 tokens per block.
// 512 threads = 8 waves = 2 token-halves x 4 concept-quarters; each wave
// owns TWO 32-token groups (acc 2x4 f32x16 = 128 AGPR) so every B fragment
// read from LDS feeds 2 MFMAs. B in 4 x 16 KB LDS ring (BK=16, 32 phases),
// counted-vmcnt: stage(p+3) at phase p; boundary waits vmcnt(8)/(4)/(0).
// 1 block/CU (VGPR-limited); numerics identical to the BM=64 version.
__global__ __launch_bounds__(512, 2)
void k_main(const int* __restrict__ doc, const float* __restrict__ cw,
            const float* __restrict__ n_arr,
            float* __restrict__ out, unsigned* __restrict__ counts,
            unsigned* __restrict__ binc,
            double* __restrict__ vq_acc, unsigned* __restrict__ nflag,
            unsigned* __restrict__ flag_list) {
    __shared__ f16x8 bsh[4][1024];      // 64 KB ring of K-step tiles
    __shared__ float nsl[512];
    __shared__ float nxs[128];
    __shared__ uint4 redv[8][64];       // 8 KB
    __shared__ int docs[128];
    __shared__ int idxs[128];
    __shared__ double dred[512];        // 4 KB

    const int tid   = threadIdx.x;
    const int n0    = blockIdx.x * 128;
    const int lane  = tid & 63;
    const int wv    = tid >> 6;
    const int wm    = wv >> 2;          // token half 0/1 (64 tokens each)
    const int wq    = wv & 3;           // concept quarter
    const int hv    = lane >> 5;
    const int ln31  = lane & 31;
    const int cbase = wq * 128 + ln31;

    if (tid < 128) docs[tid] = doc[n0 + tid];
    nsl[tid] = n_arr[tid];
    __syncthreads();

#define STAGE16(P, DST)                                                       \
    {                                                                         \
        const char* srcb = (const char*)g_B1 + (size_t)(P) * 16384;           \
        char* dstb = (char*)(DST);                                            \
        gload16(srcb + tid * 16, dstb + tid * 16);                            \
        gload16(srcb + 8192 + tid * 16, dstb + 8192 + tid * 16);              \
    }

    const char* aptrA = (const char*)(g_A16 + (size_t)docs[wm * 64 + ln31] * DIM);
    const char* aptrB = (const char*)(g_A16 + (size_t)docs[wm * 64 + 32 + ln31] * DIM);

    // prologue: stage steps 0..2; A(0..2) for both groups; nx from table
    STAGE16(0, bsh[0]);
    STAGE16(1, bsh[1]);
    STAGE16(2, bsh[2]);
    f16x8 x0a = *(const f16x8*)(aptrA + (hv * 8) * 2);
    f16x8 x1a = *(const f16x8*)(aptrA + (16 + hv * 8) * 2);
    f16x8 x2a = *(const f16x8*)(aptrA + (32 + hv * 8) * 2);
    f16x8 x0b = *(const f16x8*)(aptrB + (hv * 8) * 2);
    f16x8 x1b = *(const f16x8*)(aptrB + (16 + hv * 8) * 2);
    f16x8 x2b = *(const f16x8*)(aptrB + (32 + hv * 8) * 2);
    if (tid < 128) nxs[tid] = g_NW[docs[tid]];
    __syncthreads();   // one-time full drain: stages 0-2 + A + nxs

    f32x16 accA[4], accB[4];
    #pragma unroll
    for (int n = 0; n < 4; ++n) { accA[n] = (f32x16)(0.0f); accB[n] = (f32x16)(0.0f); }

    #pragma unroll
    for (int p = 0; p < 32; ++p) {
        if (p >= 1) {
            __builtin_amdgcn_sched_barrier(0);
            if (p <= 29)      asm volatile("s_waitcnt vmcnt(8)" ::: "memory");
            else if (p == 30) asm volatile("s_waitcnt vmcnt(4)" ::: "memory");
            else              asm volatile("s_waitcnt vmcnt(0)" ::: "memory");
            __builtin_amdgcn_sched_barrier(0);
            __builtin_amdgcn_s_barrier();
            __builtin_amdgcn_sched_barrier(0);
        }
        f16x8 naA = x2a, naB = x2b;
        if (p + 3 < 32) {
            naA = *(const f16x8*)(aptrA + ((p + 3) * 16 + hv * 8) * 2);
            naB = *(const f16x8*)(aptrB + ((p + 3) * 16 + hv * 8) * 2);
            __builtin_amdgcn_sched_barrier(0);
            STAGE16(p + 3, bsh[(p + 3) & 3]);
            __builtin_amdgcn_sched_barrier(0);
        }
        const f16x8* bb = bsh[p & 3];
        #pragma unroll
        for (int n = 0; n < 4; ++n) {
            f16x8 b = bb[hv * 512 + cbase + n * 32];
            accA[n] = __builtin_amdgcn_mfma_f32_32x32x16_f16(x0a, b, accA[n], 0, 0, 0);
            accB[n] = __builtin_amdgcn_mfma_f32_32x32x16_f16(x0b, b, accB[n], 0, 0, 0);
        }
        x0a = x1a; x1a = x2a; x2a = naA;
        x0b = x1b; x1b = x2b; x2b = naB;
    }
#undef STAGE16
    __syncthreads();   // K-loop done

    float nsv[4];
    #pragma unroll
    for (int n = 0; n < 4; ++n) nsv[n] = nsl[cbase + n * 32];

    // per-row argmin + second best; C/D: col=lane&31, row=(r&3)+8*(r>>2)+4*hv
    // acc holds S = x_h . (512 c)_h ; d = fmaf(-2^-8, S, nx+nc)
    #pragma unroll
    for (int g = 0; g < 2; ++g) {
        const f32x16* am = g ? accB : accA;
        #pragma unroll
        for (int r = 0; r < 16; ++r) {
            int tt = (r & 3) + ((r >> 2) << 3) + (hv << 2);   // 0..31
            float nxr = nxs[wm * 64 + g * 32 + tt];
            float v1 = INFINITY, v2 = INFINITY; int j1 = 0x7fffffff;
            #pragma unroll
            for (int n = 0; n < 4; ++n) {
                float d = fmaf(-0.00390625f, am[n][r], nxr + nsv[n]);
                int jj = cbase + n * 32;
                if (d < v1) { v2 = v1; v1 = d; j1 = jj; }
                else if (d < v2) { v2 = d; }
            }
            #pragma unroll
            for (int off = 1; off < 32; off <<= 1) {
                float ov1 = __shfl_xor(v1, off);
                int   oj1 = __shfl_xor(j1, off);
                float ov2 = __shfl_xor(v2, off);
                v2 = fminf(fminf(v2, ov2), fmaxf(v1, ov1));
                bool take = (ov1 < v1) || (ov1 == v1 && oj1 < j1);
                if (take) { v1 = ov1; j1 = oj1; }
            }
            if (ln31 == 0)
                redv[wv][g * 32 + tt] = make_uint4(__float_as_uint(v1), (unsigned)j1,
                                                   __float_as_uint(v2), 0u);
        }
    }
    __syncthreads();
    double myv1 = 0.0;
    if (tid < 128) {
        int wmt = tid >> 6, loc = tid & 63;
        uint4 a = redv[wmt * 4][loc];
        float v1 = __uint_as_float(a.x), v2 = __uint_as_float(a.z);
        int j1 = (int)a.y;
        #pragma unroll
        for (int w = 1; w < 4; ++w) {
            uint4 b = redv[wmt * 4 + w][loc];
            float wv1 = __uint_as_float(b.x), wv2 = __uint_as_float(b.z);
            v2 = fminf(fminf(v2, wv2), fmaxf(v1, wv1));
            bool take = (wv1 < v1) || (wv1 == v1 && (int)b.y < j1);
            if (take) { v1 = wv1; j1 = (int)b.y; }
        }
        idxs[tid] = j1;
        atomicAdd(&counts[j1], 1u);
        atomicAdd(&binc[docs[tid]], 1u);
        myv1 = (double)v1;
        if (v2 - v1 <= 2e-6f) {           // ~8 sigma of fp16-path noise
            unsigned pq = atomicAdd(nflag, 1u);
            if (pq < FLAG_CAP) flag_list[pq] = (unsigned)(n0 + tid);
        }
    }
    dred[tid] = myv1;
    __syncthreads();

    // encodings: one-hot rows (nontemporal streaming output; pure stores)
    for (int lin = tid; lin < 16384; lin += 512) {
        int t = lin >> 7, f4 = lin & 127;
        int idx = idxs[t];
        int b4 = f4 << 2;
        f32x4 v;
        v.x = (idx == b4)     ? 1.f : 0.f;
        v.y = (idx == b4 + 1) ? 1.f : 0.f;
        v.z = (idx == b4 + 2) ? 1.f : 0.f;
        v.w = (idx == b4 + 3) ? 1.f : 0.f;
        __builtin_nontemporal_store(v,
            (f32x4*)(out + OFF_ENC + ((size_t)(n0 + t) << 9) + (size_t)b4));
    }
    // quantized_words = codebook rows
    for (int lin = tid; lin < 16384; lin += 512) {
        int t = lin >> 7, f4 = lin & 127;
        f32x4 c4 = *(const f32x4*)(cw + (size_t)idxs[t] * DIM + (f4 << 2));
        __builtin_nontemporal_store(c4,
            (f32x4*)(out + OFF_QW + ((size_t)(n0 + t) << 9) + (size_t)(f4 << 2)));
    }
    // vq partial reduce (flagged tokens patched exactly by k_fixup)
    for (int st = 256; st; st >>= 1) {
        if (tid < st) dred[tid] += dred[tid + st];
        __syncthreads();
    }
    if (tid == 0) atomicAdd(vq_acc, dred[0]);
}

// ---------------------------------------------------------------------------
// Exact fp32 recompute for flagged near-tie tokens (vectorized, grid-stride).
__global__ __launch_bounds__(512)
void k_fixup(const int* __restrict__ doc, const float* __restrict__ emb,
             const float* __restrict__ cw, const float* __restrict__ n_arr,
             const float* __restrict__ nw,
             const unsigned* __restrict__ nflag, const unsigned* __restrict__ flag_list,
             float* __restrict__ out, unsigned* __restrict__ counts,
             double* __restrict__ vq_acc) {
    __shared__ float4 xs4[128];
    __shared__ int oldj_sh;
    __shared__ float vsh[512];
    __shared__ unsigned long long keys[512];

    const int tid = threadIdx.x;
    unsigned nf = *nflag;
    if (nf > FLAG_CAP) nf = FLAG_CAP;

    for (unsigned f = blockIdx.x; f < nf; f += gridDim.x) {
        int t = (int)flag_list[f];
        int dc = doc[t];
        float nxf = nw[dc];
        if (tid < 128)
            xs4[tid] = *(const float4*)(emb + (size_t)dc * DIM + tid * 4);
        if (tid == 0) oldj_sh = -1;
        __syncthreads();
        {
            float e = out[OFF_ENC + (size_t)t * 512 + tid];
            if (e == 1.0f) oldj_sh = tid;
        }
        {
            const float4* cr = (const float4*)(cw + (size_t)tid * DIM);
            float acc = 0.f;
            #pragma unroll 8
            for (int fq = 0; fq < 128; ++fq) {
                float4 c4 = cr[fq], x4 = xs4[fq];
                acc = fmaf(x4.x, c4.x, acc);
                acc = fmaf(x4.y, c4.y, acc);
                acc = fmaf(x4.z, c4.z, acc);
                acc = fmaf(x4.w, c4.w, acc);
            }
            float v = fmaf(-2.f, acc, nxf + n_arr[tid]);
            vsh[tid] = v;
            keys[tid] = (((unsigned long long)__float_as_uint(v)) << 32) | (unsigned)tid;
        }
        __syncthreads();
        for (int st = 256; st; st >>= 1) {
            if (tid < st) {
                unsigned long long o = keys[tid + st];
                if (o < keys[tid]) keys[tid] = o;
            }
            __syncthreads();
        }
        int newj = (int)(keys[0] & 0xffffffffu);
        int oldj = oldj_sh;
        if (newj != oldj) {
            if (tid == 0) {
                out[OFF_ENC + (size_t)t * 512 + oldj] = 0.0f;
                out[OFF_ENC + (size_t)t * 512 + newj] = 1.0f;
                atomicSub(&counts[oldj], 1u);
                atomicAdd(&counts[newj], 1u);
                atomicAdd(vq_acc, (double)vsh[newj] - (double)vsh[oldj]);
            }
            if (tid < 128) {
                float4 cn = *(const float4*)(cw + (size_t)newj * DIM + tid * 4);
                *(float4*)&out[OFF_QW + (size_t)t * 512 + tid * 4] = cn;
            }
        }
        __syncthreads();
    }
}

// ---------------------------------------------------------------------------
__global__ void k_docu(const unsigned* __restrict__ counts,
                       const float* __restrict__ cw, float* __restrict__ out_docu) {
    __shared__ float cnt[512];
    int tid = threadIdx.x;
    cnt[tid] = (float)counts[tid];
    __syncthreads();
    double a = 0.0;
    for (int j = 0; j < K_CON; ++j)
        a += (double)cnt[j] * (double)cw[(size_t)j * DIM + tid];
    out_docu[tid] = (float)(a * (1.0 / (double)N_TOK));
}

// ---------------------------------------------------------------------------
// lts via MFMA on fp16 (512*c): one wave per 32x32 tile of the KxK Gram.
// dd = n_i + n_j - 2*(acc/512^2) + 2e-6*(s_i - s_j) + 512e-12.
__global__ __launch_bounds__(256)
void k_ltsm(const float* __restrict__ n_arr, const float* __restrict__ s_arr,
            double* __restrict__ lts_acc) {
    const int tid  = threadIdx.x;
    const int lane = tid & 63;
    const int wv   = tid >> 6;
    const int hv   = lane >> 5;
    const int ln31 = lane & 31;
    const int tile = blockIdx.x * 4 + wv;   // 0..255
    const int ti = tile >> 4, tj = tile & 15;

    const f16x8* bt = (const f16x8*)g_B1;
    f32x16 acc = (f32x16)(0.0f);
    #pragma unroll
    for (int s = 0; s < 32; ++s) {
        f16x8 af = bt[((size_t)s * 2 + hv) * 512 + ti * 32 + ln31];
        f16x8 bf = bt[((size_t)s * 2 + hv) * 512 + tj * 32 + ln31];
        acc = __builtin_amdgcn_mfma_f32_32x32x16_f16(af, bf, acc, 0, 0, 0);
    }

    const int j = tj * 32 + ln31;
    const float nj = n_arr[j], sj = s_arr[j];
    const float EPS = 1e-6f;
    double lsum = 0.0;
    #pragma unroll
    for (int r = 0; r < 16; ++r) {
        int row = (r & 3) + ((r >> 2) << 3) + (hv << 2);
        int i = ti * 32 + row;
        float ddv = n_arr[i] + nj
                  + fmaf(-2.0f / 262144.0f, acc[r],
                         2.f * EPS * (s_arr[i] - sj) + 512.f * EPS * EPS);
        float dist = sqrtf(fmaxf(ddv, 0.f));
        lsum += (double)((i == j) ? dist : fmaxf(0.f, 1.f - dist));
    }
    for (int off = 32; off; off >>= 1) lsum += __shfl_down(lsum, off);
    if (lane == 0) atomicAdd(lts_acc, lsum);
}

// logits -> e = exp(logit + bias), per-block partial sums (uncontended)
__global__ void k_logexp(const float* __restrict__ docu, const float* __restrict__ q2w,
                         const float* __restrict__ q2b, float* __restrict__ evals,
                         double* __restrict__ parts) {
    __shared__ double esh[4];
    int wvi = threadIdx.x >> 6, lane = threadIdx.x & 63;
    int v = blockIdx.x * 4 + wvi;
    if (lane == 0) esh[wvi] = 0.0;
    if (v < VOCAB) {
        const float* wr = q2w + (size_t)v * DIM;
        float4 a = *(const float4*)(wr + lane*8);
        float4 b = *(const float4*)(wr + lane*8 + 4);
        float4 da = *(const float4*)(docu + lane*8);
        float4 db = *(const float4*)(docu + lane*8 + 4);
        float p = a.x*da.x + a.y*da.y + a.z*da.z + a.w*da.w
                + b.x*db.x + b.y*db.y + b.z*db.z + b.w*db.w;
        for (int off = 32; off; off >>= 1) p += __shfl_down(p, off);
        if (lane == 0) {
            float e = expf(p + q2b[v]);
            evals[v] = e;
            esh[wvi] = (double)e;
        }
    }
    __syncthreads();
    if (threadIdx.x == 0)
        parts[blockIdx.x] = esh[0] + esh[1] + esh[2] + esh[3];
}

__global__ void k_sumred(const double* __restrict__ parts, double* __restrict__ sumv) {
    __shared__ double red[256];
    int tid = threadIdx.x;
    double s = 0.0;
    for (int i = tid; i < NPARTS; i += 256) s += parts[i];
    red[tid] = s; __syncthreads();
    for (int st = 128; st; st >>= 1) {
        if (tid < st) red[tid] += red[tid + st];
        __syncthreads();
    }
    if (tid == 0) *sumv = red[0];
}

__global__ void k_final(const float* __restrict__ evals,
                        const double* __restrict__ sumv, const unsigned* __restrict__ binc,
                        const double* __restrict__ vq_acc, const double* __restrict__ lts_acc,
                        float* __restrict__ out) {
    int v = blockIdx.x * 256 + threadIdx.x;
    if (v < VOCAB) {
        float s = (float)(*sumv);
        float p = evals[v] / s;
        out[OFF_OUT + v] = logf(p + 1e-6f) * (float)binc[v];
    }
    if (v == 0) {
        out[OFF_VQ]  = (float)(1.25 * (*vq_acc) * (1.0 / 67108864.0));
        out[OFF_LTS] = (float)((*lts_acc) * (1.0 / 262144.0));
    }
}

// ---------------------------------------------------------------------------
extern "C" void kernel_launch(void* const* d_in, const int* in_sizes, int n_in,
                              void* d_out, int out_size, void* d_ws, size_t ws_size,
                              hipStream_t stream) {
    const int*   doc = (const int*)d_in[0];
    const float* emb = (const float*)d_in[1];
    const float* cw  = (const float*)d_in[2];
    const float* q2w = (const float*)d_in[3];
    const float* q2b = (const float*)d_in[4];
    float* out = (float*)d_out;
    char* ws = (char*)d_ws;

    unsigned* counts = (unsigned*)(ws + WS_COUNTS);
    double*   vq_acc = (double*)(ws + WS_VQ);
    double*   lts_acc= (double*)(ws + WS_LTS);
    double*   sumv   = (double*)(ws + WS_SUMV);
    unsigned* nflag  = (unsigned*)(ws + WS_NFLAG);
    float*    n_arr  = (float*)(ws + WS_NARR);
    float*    s_arr  = (float*)(ws + WS_SARR);
    unsigned* binc   = (unsigned*)(ws + WS_BINC);
    float*    evals  = (float*)(ws + WS_LOGITS);
    unsigned* flags  = (unsigned*)(ws + WS_FLAGS);
    double*   parts  = (double*)(ws + WS_PART);

    _Float16* b1;  hipGetSymbolAddress((void**)&b1,  HIP_SYMBOL(g_B1));
    _Float16* a16; hipGetSymbolAddress((void**)&a16, HIP_SYMBOL(g_A16));
    float*    nw;  hipGetSymbolAddress((void**)&nw,  HIP_SYMBOL(g_NW));

    // scalars zeroed by k_nsprep block 0, binc by k_prepa

    hipLaunchKernelGGL(k_nsprep, dim3(128),   dim3(256), 0, stream, cw, n_arr, s_arr,
                       b1, (uint4*)ws);
    hipLaunchKernelGGL(k_prepa,  dim3(NPARTS), dim3(256), 0, stream, emb, a16, nw, binc);
    hipLaunchKernelGGL(k_main,   dim3(1024),  dim3(512), 0, stream, doc, cw, n_arr,
                       out, counts, binc, vq_acc, nflag, flags);
    hipLaunchKernelGGL(k_fixup,  dim3(2048),  dim3(512), 0, stream, doc, emb, cw, n_arr,
                       nw, nflag, flags, out, counts, vq_acc);
    hipLaunchKernelGGL(k_docu,   dim3(1),     dim3(512), 0, stream, counts, cw, out + OFF_DOCU);
    hipLaunchKernelGGL(k_ltsm,   dim3(64),    dim3(256), 0, stream, n_arr, s_arr, lts_acc);
    hipLaunchKernelGGL(k_logexp, dim3(NPARTS), dim3(256), 0, stream,
                       out + OFF_DOCU, q2w, q2b, evals, parts);
    hipLaunchKernelGGL(k_sumred, dim3(1), dim3(256), 0, stream, parts, sumv);
    hipLaunchKernelGGL(k_final,  dim3((VOCAB + 255) / 256), dim3(256), 0, stream,
                       evals, sumv, binc, vq_acc, lts_acc, out);
}

// Round 16
// 379.826 us; speedup vs baseline: 1.1828x; 1.1828x over previous
//
#include <hip/hip_runtime.h>
#include <math.h>

#define N_TOK 131072
#define VOCAB 50257
#define DIM   512
#define K_CON 512
#define NPARTS 12565   // ceil(VOCAB/4)

// d_out layout (float32 elements)
#define OFF_ENC  ((size_t)0)
#define OFF_QW   ((size_t)67108864)
#define OFF_DOCU ((size_t)134217728)
#define OFF_OUT  ((size_t)134218240)
#define OFF_VQ   ((size_t)134268497)
#define OFF_LTS  ((size_t)134268498)

// ws layout (bytes)
#define WS_COUNTS 0        // 512 * u32
#define WS_VQ     2048     // double
#define WS_LTS    2056     // double
#define WS_SUMV   2072     // double
#define WS_NFLAG  2080     // u32
#define WS_NARR   4096     // 512 f32
#define WS_SARR   6144     // 512 f32
#define WS_BINC   8192     // VOCAB u32
#define WS_LOGITS 209920   // VOCAB f32 (holds exp(logit))
#define WS_FLAGS  411648   // FLAG_CAP u32  (ends 542720)
#define WS_PART   544768   // NPARTS double (ends 645288)
#define FLAG_CAP  32768

typedef __attribute__((ext_vector_type(4)))  float f32x4;
typedef __attribute__((ext_vector_type(8)))  _Float16 f16x8;
typedef __attribute__((ext_vector_type(16))) float f32x16;

// Codebook as fp16 of (512*c): frag [(s*2+hf)*512 + c] x f16x8. 512 KB.
// K-step tile s = 16 KB at byte offset s*16384 (first 8 KB hf=0, then hf=1).
__device__ _Float16 g_B1[32 * 2 * 512 * 8];
// Embedding table as fp16 (unscaled), row-major [VOCAB][512]. ~51.5 MB.
__device__ _Float16 g_A16[(size_t)VOCAB * DIM];
// Per-vocab-row |x|^2 (double-accumulated, rounded to f32).
__device__ float g_NW[VOCAB];

__device__ inline void gload16(const void* g, void* l) {
    __builtin_amdgcn_global_load_lds(
        (const __attribute__((address_space(1))) unsigned int*)g,
        (__attribute__((address_space(3))) unsigned int*)l, 16, 0, 0);
}

// ---------------------------------------------------------------------------
// merged: n/s arrays + codebook fp16 (512*c) prep + ws scalar zeroing
__global__ void k_nsprep(const float* __restrict__ cw, float* __restrict__ n_arr,
                         float* __restrict__ s_arr, _Float16* __restrict__ b1,
                         uint4* __restrict__ wz) {
    if (blockIdx.x == 0) {
        uint4 z; z.x = 0u; z.y = 0u; z.z = 0u; z.w = 0u;
        wz[threadIdx.x] = z;          // 256 * 16 B = 4 KB scalar region
    }
    int w = threadIdx.x >> 6, lane = threadIdx.x & 63;
    int r = blockIdx.x * 4 + w;
    const float* row = cw + (size_t)r * DIM;
    {
        float4 a = *(const float4*)(row + lane * 8);
        float4 b = *(const float4*)(row + lane * 8 + 4);
        float v[8] = {a.x,a.y,a.z,a.w,b.x,b.y,b.z,b.w};
        double na = 0.0, sa = 0.0;
        #pragma unroll
        for (int e = 0; e < 8; ++e) { na += (double)v[e]*v[e]; sa += (double)v[e]; }
        for (int off = 32; off; off >>= 1) {
            na += __shfl_down(na, off);
            sa += __shfl_down(sa, off);
        }
        if (lane == 0) { n_arr[r] = (float)na; s_arr[r] = (float)sa; }
    }
    {
        int s = lane >> 1, hf = lane & 1;
        const float* p = row + s * 16 + hf * 8;
        float4 xa = *(const float4*)p;
        float4 xb = *(const float4*)(p + 4);
        float xf[8] = {xa.x,xa.y,xa.z,xa.w,xb.x,xb.y,xb.z,xb.w};
        f16x8 h8;
        #pragma unroll
        for (int e = 0; e < 8; ++e) h8[e] = (_Float16)(xf[e] * 512.0f);
        *(f16x8*)&b1[(((size_t)s * 2 + hf) * 512 + r) * 8] = h8;
    }
}

// ---------------------------------------------------------------------------
// emb -> fp16 table + per-row |x|^2 + binc zeroing (covers all VOCAB rows)
__global__ void k_prepa(const float* __restrict__ emb, _Float16* __restrict__ a16,
                        float* __restrict__ nw, unsigned* __restrict__ binc) {
    int wv = threadIdx.x >> 6, lane = threadIdx.x & 63;
    int r = blockIdx.x * 4 + wv;
    if (r >= VOCAB) return;
    const float* row = emb + (size_t)r * DIM;
    float4 a = *(const float4*)(row + lane * 8);
    float4 b = *(const float4*)(row + lane * 8 + 4);
    float v[8] = {a.x,a.y,a.z,a.w,b.x,b.y,b.z,b.w};
    f16x8 h;
    double na = 0.0;
    #pragma unroll
    for (int e = 0; e < 8; ++e) { h[e] = (_Float16)v[e]; na += (double)v[e]*v[e]; }
    *(f16x8*)&a16[(size_t)r * DIM + lane * 8] = h;
    for (int off = 32; off; off >>= 1) na += __shfl_down(na, off);
    if (lane == 0) { nw[r] = (float)na; binc[r] = 0u; }
}

// ---------------------------------------------------------------------------
// Main: fp16 single-term MFMA distance GEMM. 512 threads = 8 waves (2
// token-groups x 4 concept-quarters). B in 4 x 16 KB LDS ring (BK=16, 32
// phases), counted-vmcnt pipeline: stage(p+3) issued at phase p; boundary
// entering p waits vmcnt(6) (tail: 3, 0) -> s_barrier. 2 blocks/CU.
__global__ __launch_bounds__(512, 4)
void k_main(const int* __restrict__ doc, const float* __restrict__ cw,
            const float* __restrict__ n_arr,
            float* __restrict__ out, unsigned* __restrict__ counts,
            unsigned* __restrict__ binc,
            double* __restrict__ vq_acc, unsigned* __restrict__ nflag,
            unsigned* __restrict__ flag_list) {
    __shared__ f16x8 bsh[4][1024];      // 64 KB ring of K-step tiles
    __shared__ float nsl[512];
    __shared__ float nxs[64];
    __shared__ uint4 redv[8][64];       // 8 KB
    __shared__ int docs[64];
    __shared__ int idxs[64];
    __shared__ double dred[512];        // 4 KB

    const int tid   = threadIdx.x;
    const int n0    = blockIdx.x * 64;
    const int lane  = tid & 63;
    const int wv    = tid >> 6;
    const int wm    = wv >> 2;          // token group 0/1
    const int wq    = wv & 3;           // concept quarter
    const int hv    = lane >> 5;
    const int ln31  = lane & 31;
    const int cbase = wq * 128 + ln31;

    if (tid < 64) docs[tid] = doc[n0 + tid];
    nsl[tid] = n_arr[tid];
    __syncthreads();

#define STAGE16(P, DST)                                                       \
    {                                                                         \
        const char* srcb = (const char*)g_B1 + (size_t)(P) * 16384;           \
        char* dstb = (char*)(DST);                                            \
        gload16(srcb + tid * 16, dstb + tid * 16);                            \
        gload16(srcb + 8192 + tid * 16, dstb + 8192 + tid * 16);              \
    }

    const char* aptr = (const char*)(g_A16 + (size_t)docs[wm * 32 + ln31] * DIM);

    // prologue: stage steps 0..2; A(0..2) to regs; nx from table
    STAGE16(0, bsh[0]);
    STAGE16(1, bsh[1]);
    STAGE16(2, bsh[2]);
    f16x8 x0 = *(const f16x8*)(aptr + (hv * 8) * 2);
    f16x8 x1 = *(const f16x8*)(aptr + (16 + hv * 8) * 2);
    f16x8 x2 = *(const f16x8*)(aptr + (32 + hv * 8) * 2);
    if (tid < 64) nxs[tid] = g_NW[docs[tid]];
    __syncthreads();   // one-time full drain: stages 0-2 + A + nxs

    f32x16 acc[4];
    #pragma unroll
    for (int n = 0; n < 4; ++n) acc[n] = (f32x16)(0.0f);

    #pragma unroll
    for (int p = 0; p < 32; ++p) {
        if (p >= 1) {
            __builtin_amdgcn_sched_barrier(0);
            if (p <= 29)      asm volatile("s_waitcnt vmcnt(6)" ::: "memory");
            else if (p == 30) asm volatile("s_waitcnt vmcnt(3)" ::: "memory");
            else              asm volatile("s_waitcnt vmcnt(0)" ::: "memory");
            __builtin_amdgcn_sched_barrier(0);
            __builtin_amdgcn_s_barrier();
            __builtin_amdgcn_sched_barrier(0);
        }
        f16x8 na = x2;
        if (p + 3 < 32) {
            na = *(const f16x8*)(aptr + ((p + 3) * 16 + hv * 8) * 2);
            __builtin_amdgcn_sched_barrier(0);
            STAGE16(p + 3, bsh[(p + 3) & 3]);
            __builtin_amdgcn_sched_barrier(0);
        }
        const f16x8* bb = bsh[p & 3];
        #pragma unroll
        for (int n = 0; n < 4; ++n) {
            f16x8 b = bb[hv * 512 + cbase + n * 32];
            acc[n] = __builtin_amdgcn_mfma_f32_32x32x16_f16(x0, b, acc[n], 0, 0, 0);
        }
        x0 = x1; x1 = x2; x2 = na;
    }
#undef STAGE16
    __syncthreads();   // K-loop done

    float nsv[4];
    #pragma unroll
    for (int n = 0; n < 4; ++n) nsv[n] = nsl[cbase + n * 32];

    // per-row argmin + second best; C/D: col=lane&31, row=(r&3)+8*(r>>2)+4*hv
    // acc holds S = x_h . (512 c)_h ; d = fmaf(-2^-8, S, nx+nc)
    #pragma unroll
    for (int r = 0; r < 16; ++r) {
        int tt = (r & 3) + ((r >> 2) << 3) + (hv << 2);   // 0..31 within wm
        float nxr = nxs[wm * 32 + tt];
        float v1 = INFINITY, v2 = INFINITY; int j1 = 0x7fffffff;
        #pragma unroll
        for (int n = 0; n < 4; ++n) {
            float d = fmaf(-0.00390625f, acc[n][r], nxr + nsv[n]);
            int jj = cbase + n * 32;
            if (d < v1) { v2 = v1; v1 = d; j1 = jj; }
            else if (d < v2) { v2 = d; }
        }
        #pragma unroll
        for (int off = 1; off < 32; off <<= 1) {
            float ov1 = __shfl_xor(v1, off);
            int   oj1 = __shfl_xor(j1, off);
            float ov2 = __shfl_xor(v2, off);
            v2 = fminf(fminf(v2, ov2), fmaxf(v1, ov1));
            bool take = (ov1 < v1) || (ov1 == v1 && oj1 < j1);
            if (take) { v1 = ov1; j1 = oj1; }
        }
        if (ln31 == 0)
            redv[wv][wm * 32 + tt] = make_uint4(__float_as_uint(v1), (unsigned)j1,
                                                __float_as_uint(v2), 0u);
    }
    __syncthreads();
    double myv1 = 0.0;
    if (tid < 64) {
        int g = tid >> 5;   // token group
        uint4 a = redv[g * 4][tid];
        float v1 = __uint_as_float(a.x), v2 = __uint_as_float(a.z);
        int j1 = (int)a.y;
        #pragma unroll
        for (int w = 1; w < 4; ++w) {
            uint4 b = redv[g * 4 + w][tid];
            float wv1 = __uint_as_float(b.x), wv2 = __uint_as_float(b.z);
            v2 = fminf(fminf(v2, wv2), fmaxf(v1, wv1));
            bool take = (wv1 < v1) || (wv1 == v1 && (int)b.y < j1);
            if (take) { v1 = wv1; j1 = (int)b.y; }
        }
        idxs[tid] = j1;
        atomicAdd(&counts[j1], 1u);
        atomicAdd(&binc[docs[tid]], 1u);
        myv1 = (double)v1;
        if (v2 - v1 <= 2e-6f) {           // ~8 sigma of fp16-path noise
            unsigned pq = atomicAdd(nflag, 1u);
            if (pq < FLAG_CAP) flag_list[pq] = (unsigned)(n0 + tid);
        }
    }
    dred[tid] = myv1;
    __syncthreads();

    // encodings: one-hot rows (nontemporal streaming output; pure stores)
    for (int lin = tid; lin < 8192; lin += 512) {
        int t = lin >> 7, f4 = lin & 127;
        int idx = idxs[t];
        int b4 = f4 << 2;
        f32x4 v;
        v.x = (idx == b4)     ? 1.f : 0.f;
        v.y = (idx == b4 + 1) ? 1.f : 0.f;
        v.z = (idx == b4 + 2) ? 1.f : 0.f;
        v.w = (idx == b4 + 3) ? 1.f : 0.f;
        __builtin_nontemporal_store(v,
            (f32x4*)(out + OFF_ENC + ((size_t)(n0 + t) << 9) + (size_t)b4));
    }
    // quantized_words = codebook rows
    for (int lin = tid; lin < 8192; lin += 512) {
        int t = lin >> 7, f4 = lin & 127;
        f32x4 c4 = *(const f32x4*)(cw + (size_t)idxs[t] * DIM + (f4 << 2));
        __builtin_nontemporal_store(c4,
            (f32x4*)(out + OFF_QW + ((size_t)(n0 + t) << 9) + (size_t)(f4 << 2)));
    }
    // vq partial reduce (flagged tokens patched exactly by k_fixup)
    for (int st = 256; st; st >>= 1) {
        if (tid < st) dred[tid] += dred[tid + st];
        __syncthreads();
    }
    if (tid == 0) atomicAdd(vq_acc, dred[0]);
}

// ---------------------------------------------------------------------------
// Exact fp32 recompute for flagged near-tie tokens (vectorized, grid-stride).
__global__ __launch_bounds__(512)
void k_fixup(const int* __restrict__ doc, const float* __restrict__ emb,
             const float* __restrict__ cw, const float* __restrict__ n_arr,
             const float* __restrict__ nw,
             const unsigned* __restrict__ nflag, const unsigned* __restrict__ flag_list,
             float* __restrict__ out, unsigned* __restrict__ counts,
             double* __restrict__ vq_acc) {
    __shared__ float4 xs4[128];
    __shared__ int oldj_sh;
    __shared__ float vsh[512];
    __shared__ unsigned long long keys[512];

    const int tid = threadIdx.x;
    unsigned nf = *nflag;
    if (nf > FLAG_CAP) nf = FLAG_CAP;

    for (unsigned f = blockIdx.x; f < nf; f += gridDim.x) {
        int t = (int)flag_list[f];
        int dc = doc[t];
        float nxf = nw[dc];
        if (tid < 128)
            xs4[tid] = *(const float4*)(emb + (size_t)dc * DIM + tid * 4);
        if (tid == 0) oldj_sh = -1;
        __syncthreads();
        {
            float e = out[OFF_ENC + (size_t)t * 512 + tid];
            if (e == 1.0f) oldj_sh = tid;
        }
        {
            const float4* cr = (const float4*)(cw + (size_t)tid * DIM);
            float acc = 0.f;
            #pragma unroll 8
            for (int fq = 0; fq < 128; ++fq) {
                float4 c4 = cr[fq], x4 = xs4[fq];
                acc = fmaf(x4.x, c4.x, acc);
                acc = fmaf(x4.y, c4.y, acc);
                acc = fmaf(x4.z, c4.z, acc);
                acc = fmaf(x4.w, c4.w, acc);
            }
            float v = fmaf(-2.f, acc, nxf + n_arr[tid]);
            vsh[tid] = v;
            keys[tid] = (((unsigned long long)__float_as_uint(v)) << 32) | (unsigned)tid;
        }
        __syncthreads();
        for (int st = 256; st; st >>= 1) {
            if (tid < st) {
                unsigned long long o = keys[tid + st];
                if (o < keys[tid]) keys[tid] = o;
            }
            __syncthreads();
        }
        int newj = (int)(keys[0] & 0xffffffffu);
        int oldj = oldj_sh;
        if (newj != oldj) {
            if (tid == 0) {
                out[OFF_ENC + (size_t)t * 512 + oldj] = 0.0f;
                out[OFF_ENC + (size_t)t * 512 + newj] = 1.0f;
                atomicSub(&counts[oldj], 1u);
                atomicAdd(&counts[newj], 1u);
                atomicAdd(vq_acc, (double)vsh[newj] - (double)vsh[oldj]);
            }
            if (tid < 128) {
                float4 cn = *(const float4*)(cw + (size_t)newj * DIM + tid * 4);
                *(float4*)&out[OFF_QW + (size_t)t * 512 + tid * 4] = cn;
            }
        }
        __syncthreads();
    }
}

// ---------------------------------------------------------------------------
__global__ void k_docu(const unsigned* __restrict__ counts,
                       const float* __restrict__ cw, float* __restrict__ out_docu) {
    __shared__ float cnt[512];
    int tid = threadIdx.x;
    cnt[tid] = (float)counts[tid];
    __syncthreads();
    double a = 0.0;
    for (int j = 0; j < K_CON; ++j)
        a += (double)cnt[j] * (double)cw[(size_t)j * DIM + tid];
    out_docu[tid] = (float)(a * (1.0 / (double)N_TOK));
}

// ---------------------------------------------------------------------------
// lts via MFMA on fp16 (512*c): one wave per 32x32 tile of the KxK Gram.
// dd = n_i + n_j - 2*(acc/512^2) + 2e-6*(s_i - s_j) + 512e-12.
__global__ __launch_bounds__(256)
void k_ltsm(const float* __restrict__ n_arr, const float* __restrict__ s_arr,
            double* __restrict__ lts_acc) {
    const int tid  = threadIdx.x;
    const int lane = tid & 63;
    const int wv   = tid >> 6;
    const int hv   = lane >> 5;
    const int ln31 = lane & 31;
    const int tile = blockIdx.x * 4 + wv;   // 0..255
    const int ti = tile >> 4, tj = tile & 15;

    const f16x8* bt = (const f16x8*)g_B1;
    f32x16 acc = (f32x16)(0.0f);
    #pragma unroll
    for (int s = 0; s < 32; ++s) {
        f16x8 af = bt[((size_t)s * 2 + hv) * 512 + ti * 32 + ln31];
        f16x8 bf = bt[((size_t)s * 2 + hv) * 512 + tj * 32 + ln31];
        acc = __builtin_amdgcn_mfma_f32_32x32x16_f16(af, bf, acc, 0, 0, 0);
    }

    const int j = tj * 32 + ln31;
    const float nj = n_arr[j], sj = s_arr[j];
    const float EPS = 1e-6f;
    double lsum = 0.0;
    #pragma unroll
    for (int r = 0; r < 16; ++r) {
        int row = (r & 3) + ((r >> 2) << 3) + (hv << 2);
        int i = ti * 32 + row;
        float ddv = n_arr[i] + nj
                  + fmaf(-2.0f / 262144.0f, acc[r],
                         2.f * EPS * (s_arr[i] - sj) + 512.f * EPS * EPS);
        float dist = sqrtf(fmaxf(ddv, 0.f));
        lsum += (double)((i == j) ? dist : fmaxf(0.f, 1.f - dist));
    }
    for (int off = 32; off; off >>= 1) lsum += __shfl_down(lsum, off);
    if (lane == 0) atomicAdd(lts_acc, lsum);
}

// logits -> e = exp(logit + bias), per-block partial sums (uncontended)
__global__ void k_logexp(const float* __restrict__ docu, const float* __restrict__ q2w,
                         const float* __restrict__ q2b, float* __restrict__ evals,
                         double* __restrict__ parts) {
    __shared__ double esh[4];
    int wvi = threadIdx.x >> 6, lane = threadIdx.x & 63;
    int v = blockIdx.x * 4 + wvi;
    if (lane == 0) esh[wvi] = 0.0;
    if (v < VOCAB) {
        const float* wr = q2w + (size_t)v * DIM;
        float4 a = *(const float4*)(wr + lane*8);
        float4 b = *(const float4*)(wr + lane*8 + 4);
        float4 da = *(const float4*)(docu + lane*8);
        float4 db = *(const float4*)(docu + lane*8 + 4);
        float p = a.x*da.x + a.y*da.y + a.z*da.z + a.w*da.w
                + b.x*db.x + b.y*db.y + b.z*db.z + b.w*db.w;
        for (int off = 32; off; off >>= 1) p += __shfl_down(p, off);
        if (lane == 0) {
            float e = expf(p + q2b[v]);
            evals[v] = e;
            esh[wvi] = (double)e;
        }
    }
    __syncthreads();
    if (threadIdx.x == 0)
        parts[blockIdx.x] = esh[0] + esh[1] + esh[2] + esh[3];
}

__global__ void k_sumred(const double* __restrict__ parts, double* __restrict__ sumv) {
    __shared__ double red[256];
    int tid = threadIdx.x;
    double s = 0.0;
    for (int i = tid; i < NPARTS; i += 256) s += parts[i];
    red[tid] = s; __syncthreads();
    for (int st = 128; st; st >>= 1) {
        if (tid < st) red[tid] += red[tid + st];
        __syncthreads();
    }
    if (tid == 0) *sumv = red[0];
}

__global__ void k_final(const float* __restrict__ evals,
                        const double* __restrict__ sumv, const unsigned* __restrict__ binc,
                        const double* __restrict__ vq_acc, const double* __restrict__ lts_acc,
                        float* __restrict__ out) {
    int v = blockIdx.x * 256 + threadIdx.x;
    if (v < VOCAB) {
        float s = (float)(*sumv);
        float p = evals[v] / s;
        out[OFF_OUT + v] = logf(p + 1e-6f) * (float)binc[v];
    }
    if (v == 0) {
        out[OFF_VQ]  = (float)(1.25 * (*vq_acc) * (1.0 / 67108864.0));
        out[OFF_LTS] = (float)((*lts_acc) * (1.0 / 262144.0));
    }
}

// ---------------------------------------------------------------------------
extern "C" void kernel_launch(void* const* d_in, const int* in_sizes, int n_in,
                              void* d_out, int out_size, void* d_ws, size_t ws_size,
                              hipStream_t stream) {
    const int*   doc = (const int*)d_in[0];
    const float* emb = (const float*)d_in[1];
    const float* cw  = (const float*)d_in[2];
    const float* q2w = (const float*)d_in[3];
    const float* q2b = (const float*)d_in[4];
    float* out = (float*)d_out;
    char* ws = (char*)d_ws;

    unsigned* counts = (unsigned*)(ws + WS_COUNTS);
    double*   vq_acc = (double*)(ws + WS_VQ);
    double*   lts_acc= (double*)(ws + WS_LTS);
    double*   sumv   = (double*)(ws + WS_SUMV);
    unsigned* nflag  = (unsigned*)(ws + WS_NFLAG);
    float*    n_arr  = (float*)(ws + WS_NARR);
    float*    s_arr  = (float*)(ws + WS_SARR);
    unsigned* binc   = (unsigned*)(ws + WS_BINC);
    float*    evals  = (float*)(ws + WS_LOGITS);
    unsigned* flags  = (unsigned*)(ws + WS_FLAGS);
    double*   parts  = (double*)(ws + WS_PART);

    _Float16* b1;  hipGetSymbolAddress((void**)&b1,  HIP_SYMBOL(g_B1));
    _Float16* a16; hipGetSymbolAddress((void**)&a16, HIP_SYMBOL(g_A16));
    float*    nw;  hipGetSymbolAddress((void**)&nw,  HIP_SYMBOL(g_NW));

    // scalars zeroed by k_nsprep block 0, binc by k_prepa

    hipLaunchKernelGGL(k_nsprep, dim3(128),   dim3(256), 0, stream, cw, n_arr, s_arr,
                       b1, (uint4*)ws);
    hipLaunchKernelGGL(k_prepa,  dim3(NPARTS), dim3(256), 0, stream, emb, a16, nw, binc);
    hipLaunchKernelGGL(k_main,   dim3(2048),  dim3(512), 0, stream, doc, cw, n_arr,
                       out, counts, binc, vq_acc, nflag, flags);
    hipLaunchKernelGGL(k_fixup,  dim3(2048),  dim3(512), 0, stream, doc, emb, cw, n_arr,
                       nw, nflag, flags, out, counts, vq_acc);
    hipLaunchKernelGGL(k_docu,   dim3(1),     dim3(512), 0, stream, counts, cw, out + OFF_DOCU);
    hipLaunchKernelGGL(k_ltsm,   dim3(64),    dim3(256), 0, stream, n_arr, s_arr, lts_acc);
    hipLaunchKernelGGL(k_logexp, dim3(NPARTS), dim3(256), 0, stream,
                       out + OFF_DOCU, q2w, q2b, evals, parts);
    hipLaunchKernelGGL(k_sumred, dim3(1), dim3(256), 0, stream, parts, sumv);
    hipLaunchKernelGGL(k_final,  dim3((VOCAB + 255) / 256), dim3(256), 0, stream,
                       evals, sumv, binc, vq_acc, lts_acc, out);
}

// Round 17
// 371.572 us; speedup vs baseline: 1.2091x; 1.0222x over previous
//
#include <hip/hip_runtime.h>
#include <math.h>

#define N_TOK 131072
#define VOCAB 50257
#define DIM   512
#define K_CON 512
#define NPARTS 12565   // ceil(VOCAB/4)

// d_out layout (float32 elements)
#define OFF_ENC  ((size_t)0)
#define OFF_QW   ((size_t)67108864)
#define OFF_DOCU ((size_t)134217728)
#define OFF_OUT  ((size_t)134218240)
#define OFF_VQ   ((size_t)134268497)
#define OFF_LTS  ((size_t)134268498)

// ws layout (bytes)
#define WS_COUNTS 0        // 512 * u32
#define WS_VQ     2048     // double
#define WS_LTS    2056     // double
#define WS_SUMV   2072     // double
#define WS_NFLAG  2080     // u32
#define WS_NARR   4096     // 512 f32
#define WS_SARR   6144     // 512 f32
#define WS_BINC   8192     // VOCAB u32
#define WS_LOGITS 209920   // VOCAB f32 (holds exp(logit))
#define WS_FLAGS  411648   // FLAG_CAP u32  (ends 542720)
#define WS_PART   544768   // NPARTS double (ends 645288)
#define WS_DOCUD  645632   // 512 double (docu partial sums)
#define FLAG_CAP  32768

typedef __attribute__((ext_vector_type(4)))  float f32x4;
typedef __attribute__((ext_vector_type(8)))  _Float16 f16x8;
typedef __attribute__((ext_vector_type(16))) float f32x16;

// Codebook as fp16 of (512*c): frag [(s*2+hf)*512 + c] x f16x8. 512 KB.
// K-step tile s = 16 KB at byte offset s*16384 (first 8 KB hf=0, then hf=1).
__device__ _Float16 g_B1[32 * 2 * 512 * 8];
// Embedding table as fp16 (unscaled), row-major [VOCAB][512]. ~51.5 MB.
__device__ _Float16 g_A16[(size_t)VOCAB * DIM];
// Per-vocab-row |x|^2 (double-accumulated, rounded to f32).
__device__ float g_NW[VOCAB];

__device__ inline void gload16(const void* g, void* l) {
    __builtin_amdgcn_global_load_lds(
        (const __attribute__((address_space(1))) unsigned int*)g,
        (__attribute__((address_space(3))) unsigned int*)l, 16, 0, 0);
}

// ---------------------------------------------------------------------------
// merged: n/s arrays + codebook fp16 (512*c) prep + ws scratch zeroing
__global__ void k_nsprep(const float* __restrict__ cw, float* __restrict__ n_arr,
                         float* __restrict__ s_arr, _Float16* __restrict__ b1,
                         uint4* __restrict__ wz, uint4* __restrict__ wzd) {
    if (blockIdx.x == 0) {
        uint4 z; z.x = 0u; z.y = 0u; z.z = 0u; z.w = 0u;
        wz[threadIdx.x] = z;          // 256 * 16 B = 4 KB scalar region
    } else if (blockIdx.x == 1) {
        uint4 z; z.x = 0u; z.y = 0u; z.z = 0u; z.w = 0u;
        wzd[threadIdx.x] = z;         // 4 KB docu partial region
    }
    int w = threadIdx.x >> 6, lane = threadIdx.x & 63;
    int r = blockIdx.x * 4 + w;
    const float* row = cw + (size_t)r * DIM;
    {
        float4 a = *(const float4*)(row + lane * 8);
        float4 b = *(const float4*)(row + lane * 8 + 4);
        float v[8] = {a.x,a.y,a.z,a.w,b.x,b.y,b.z,b.w};
        double na = 0.0, sa = 0.0;
        #pragma unroll
        for (int e = 0; e < 8; ++e) { na += (double)v[e]*v[e]; sa += (double)v[e]; }
        for (int off = 32; off; off >>= 1) {
            na += __shfl_down(na, off);
            sa += __shfl_down(sa, off);
        }
        if (lane == 0) { n_arr[r] = (float)na; s_arr[r] = (float)sa; }
    }
    {
        int s = lane >> 1, hf = lane & 1;
        const float* p = row + s * 16 + hf * 8;
        float4 xa = *(const float4*)p;
        float4 xb = *(const float4*)(p + 4);
        float xf[8] = {xa.x,xa.y,xa.z,xa.w,xb.x,xb.y,xb.z,xb.w};
        f16x8 h8;
        #pragma unroll
        for (int e = 0; e < 8; ++e) h8[e] = (_Float16)(xf[e] * 512.0f);
        *(f16x8*)&b1[(((size_t)s * 2 + hf) * 512 + r) * 8] = h8;
    }
}

// ---------------------------------------------------------------------------
// emb -> fp16 table + per-row |x|^2 + binc zeroing (covers all VOCAB rows)
__global__ void k_prepa(const float* __restrict__ emb, _Float16* __restrict__ a16,
                        float* __restrict__ nw, unsigned* __restrict__ binc) {
    int wv = threadIdx.x >> 6, lane = threadIdx.x & 63;
    int r = blockIdx.x * 4 + wv;
    if (r >= VOCAB) return;
    const float* row = emb + (size_t)r * DIM;
    float4 a = *(const float4*)(row + lane * 8);
    float4 b = *(const float4*)(row + lane * 8 + 4);
    float v[8] = {a.x,a.y,a.z,a.w,b.x,b.y,b.z,b.w};
    f16x8 h;
    double na = 0.0;
    #pragma unroll
    for (int e = 0; e < 8; ++e) { h[e] = (_Float16)v[e]; na += (double)v[e]*v[e]; }
    *(f16x8*)&a16[(size_t)r * DIM + lane * 8] = h;
    for (int off = 32; off; off >>= 1) na += __shfl_down(na, off);
    if (lane == 0) { nw[r] = (float)na; binc[r] = 0u; }
}

// ---------------------------------------------------------------------------
// Main: fp16 single-term MFMA distance GEMM. 512 threads = 8 waves (2
// token-groups x 4 concept-quarters). B in 4 x 16 KB LDS ring (BK=16, 32
// phases), counted-vmcnt pipeline: stage(p+3) issued at phase p; boundary
// entering p waits vmcnt(6) (tail: 3, 0) -> s_barrier. 2 blocks/CU.
__global__ __launch_bounds__(512, 4)
void k_main(const int* __restrict__ doc, const float* __restrict__ cw,
            const float* __restrict__ n_arr,
            float* __restrict__ out, unsigned* __restrict__ counts,
            unsigned* __restrict__ binc,
            double* __restrict__ vq_acc, unsigned* __restrict__ nflag,
            unsigned* __restrict__ flag_list) {
    __shared__ f16x8 bsh[4][1024];      // 64 KB ring of K-step tiles
    __shared__ float nsl[512];
    __shared__ float nxs[64];
    __shared__ uint4 redv[8][64];       // 8 KB
    __shared__ int docs[64];
    __shared__ int idxs[64];
    __shared__ double dred[512];        // 4 KB

    const int tid   = threadIdx.x;
    const int n0    = blockIdx.x * 64;
    const int lane  = tid & 63;
    const int wv    = tid >> 6;
    const int wm    = wv >> 2;          // token group 0/1
    const int wq    = wv & 3;           // concept quarter
    const int hv    = lane >> 5;
    const int ln31  = lane & 31;
    const int cbase = wq * 128 + ln31;

    if (tid < 64) docs[tid] = doc[n0 + tid];
    nsl[tid] = n_arr[tid];
    __syncthreads();

#define STAGE16(P, DST)                                                       \
    {                                                                         \
        const char* srcb = (const char*)g_B1 + (size_t)(P) * 16384;           \
        char* dstb = (char*)(DST);                                            \
        gload16(srcb + tid * 16, dstb + tid * 16);                            \
        gload16(srcb + 8192 + tid * 16, dstb + 8192 + tid * 16);              \
    }

    const char* aptr = (const char*)(g_A16 + (size_t)docs[wm * 32 + ln31] * DIM);

    // prologue: stage steps 0..2; A(0..2) to regs; nx from table
    STAGE16(0, bsh[0]);
    STAGE16(1, bsh[1]);
    STAGE16(2, bsh[2]);
    f16x8 x0 = *(const f16x8*)(aptr + (hv * 8) * 2);
    f16x8 x1 = *(const f16x8*)(aptr + (16 + hv * 8) * 2);
    f16x8 x2 = *(const f16x8*)(aptr + (32 + hv * 8) * 2);
    if (tid < 64) nxs[tid] = g_NW[docs[tid]];
    __syncthreads();   // one-time full drain: stages 0-2 + A + nxs

    f32x16 acc[4];
    #pragma unroll
    for (int n = 0; n < 4; ++n) acc[n] = (f32x16)(0.0f);

    #pragma unroll
    for (int p = 0; p < 32; ++p) {
        if (p >= 1) {
            __builtin_amdgcn_sched_barrier(0);
            if (p <= 29)      asm volatile("s_waitcnt vmcnt(6)" ::: "memory");
            else if (p == 30) asm volatile("s_waitcnt vmcnt(3)" ::: "memory");
            else              asm volatile("s_waitcnt vmcnt(0)" ::: "memory");
            __builtin_amdgcn_sched_barrier(0);
            __builtin_amdgcn_s_barrier();
            __builtin_amdgcn_sched_barrier(0);
        }
        f16x8 na = x2;
        if (p + 3 < 32) {
            na = *(const f16x8*)(aptr + ((p + 3) * 16 + hv * 8) * 2);
            __builtin_amdgcn_sched_barrier(0);
            STAGE16(p + 3, bsh[(p + 3) & 3]);
            __builtin_amdgcn_sched_barrier(0);
        }
        const f16x8* bb = bsh[p & 3];
        #pragma unroll
        for (int n = 0; n < 4; ++n) {
            f16x8 b = bb[hv * 512 + cbase + n * 32];
            acc[n] = __builtin_amdgcn_mfma_f32_32x32x16_f16(x0, b, acc[n], 0, 0, 0);
        }
        x0 = x1; x1 = x2; x2 = na;
    }
#undef STAGE16
    __syncthreads();   // K-loop done

    float nsv[4];
    #pragma unroll
    for (int n = 0; n < 4; ++n) nsv[n] = nsl[cbase + n * 32];

    // per-row argmin + second best; C/D: col=lane&31, row=(r&3)+8*(r>>2)+4*hv
    // acc holds S = x_h . (512 c)_h ; d = fmaf(-2^-8, S, nx+nc)
    #pragma unroll
    for (int r = 0; r < 16; ++r) {
        int tt = (r & 3) + ((r >> 2) << 3) + (hv << 2);   // 0..31 within wm
        float nxr = nxs[wm * 32 + tt];
        float v1 = INFINITY, v2 = INFINITY; int j1 = 0x7fffffff;
        #pragma unroll
        for (int n = 0; n < 4; ++n) {
            float d = fmaf(-0.00390625f, acc[n][r], nxr + nsv[n]);
            int jj = cbase + n * 32;
            if (d < v1) { v2 = v1; v1 = d; j1 = jj; }
            else if (d < v2) { v2 = d; }
        }
        #pragma unroll
        for (int off = 1; off < 32; off <<= 1) {
            float ov1 = __shfl_xor(v1, off);
            int   oj1 = __shfl_xor(j1, off);
            float ov2 = __shfl_xor(v2, off);
            v2 = fminf(fminf(v2, ov2), fmaxf(v1, ov1));
            bool take = (ov1 < v1) || (ov1 == v1 && oj1 < j1);
            if (take) { v1 = ov1; j1 = oj1; }
        }
        if (ln31 == 0)
            redv[wv][wm * 32 + tt] = make_uint4(__float_as_uint(v1), (unsigned)j1,
                                                __float_as_uint(v2), 0u);
    }
    __syncthreads();
    double myv1 = 0.0;
    if (tid < 64) {
        int g = tid >> 5;   // token group
        uint4 a = redv[g * 4][tid];
        float v1 = __uint_as_float(a.x), v2 = __uint_as_float(a.z);
        int j1 = (int)a.y;
        #pragma unroll
        for (int w = 1; w < 4; ++w) {
            uint4 b = redv[g * 4 + w][tid];
            float wv1 = __uint_as_float(b.x), wv2 = __uint_as_float(b.z);
            v2 = fminf(fminf(v2, wv2), fmaxf(v1, wv1));
            bool take = (wv1 < v1) || (wv1 == v1 && (int)b.y < j1);
            if (take) { v1 = wv1; j1 = (int)b.y; }
        }
        idxs[tid] = j1;
        atomicAdd(&counts[j1], 1u);
        atomicAdd(&binc[docs[tid]], 1u);
        myv1 = (double)v1;
        if (v2 - v1 <= 2e-6f) {           // ~8 sigma of fp16-path noise
            unsigned pq = atomicAdd(nflag, 1u);
            if (pq < FLAG_CAP) flag_list[pq] = (unsigned)(n0 + tid);
        }
    }
    dred[tid] = myv1;
    __syncthreads();

    // encodings: one-hot rows (nontemporal streaming output; pure stores)
    for (int lin = tid; lin < 8192; lin += 512) {
        int t = lin >> 7, f4 = lin & 127;
        int idx = idxs[t];
        int b4 = f4 << 2;
        f32x4 v;
        v.x = (idx == b4)     ? 1.f : 0.f;
        v.y = (idx == b4 + 1) ? 1.f : 0.f;
        v.z = (idx == b4 + 2) ? 1.f : 0.f;
        v.w = (idx == b4 + 3) ? 1.f : 0.f;
        __builtin_nontemporal_store(v,
            (f32x4*)(out + OFF_ENC + ((size_t)(n0 + t) << 9) + (size_t)b4));
    }
    // quantized_words = codebook rows
    for (int lin = tid; lin < 8192; lin += 512) {
        int t = lin >> 7, f4 = lin & 127;
        f32x4 c4 = *(const f32x4*)(cw + (size_t)idxs[t] * DIM + (f4 << 2));
        __builtin_nontemporal_store(c4,
            (f32x4*)(out + OFF_QW + ((size_t)(n0 + t) << 9) + (size_t)(f4 << 2)));
    }
    // vq partial reduce (flagged tokens patched exactly by k_fixup)
    for (int st = 256; st; st >>= 1) {
        if (tid < st) dred[tid] += dred[tid + st];
        __syncthreads();
    }
    if (tid == 0) atomicAdd(vq_acc, dred[0]);
}

// ---------------------------------------------------------------------------
// Exact fp32 recompute for flagged near-tie tokens (vectorized, grid-stride).
__global__ __launch_bounds__(512)
void k_fixup(const int* __restrict__ doc, const float* __restrict__ emb,
             const float* __restrict__ cw, const float* __restrict__ n_arr,
             const float* __restrict__ nw,
             const unsigned* __restrict__ nflag, const unsigned* __restrict__ flag_list,
             float* __restrict__ out, unsigned* __restrict__ counts,
             double* __restrict__ vq_acc) {
    __shared__ float4 xs4[128];
    __shared__ int oldj_sh;
    __shared__ float vsh[512];
    __shared__ unsigned long long keys[512];

    const int tid = threadIdx.x;
    unsigned nf = *nflag;
    if (nf > FLAG_CAP) nf = FLAG_CAP;

    for (unsigned f = blockIdx.x; f < nf; f += gridDim.x) {
        int t = (int)flag_list[f];
        int dc = doc[t];
        float nxf = nw[dc];
        if (tid < 128)
            xs4[tid] = *(const float4*)(emb + (size_t)dc * DIM + tid * 4);
        if (tid == 0) oldj_sh = -1;
        __syncthreads();
        {
            float e = out[OFF_ENC + (size_t)t * 512 + tid];
            if (e == 1.0f) oldj_sh = tid;
        }
        {
            const float4* cr = (const float4*)(cw + (size_t)tid * DIM);
            float acc = 0.f;
            #pragma unroll 8
            for (int fq = 0; fq < 128; ++fq) {
                float4 c4 = cr[fq], x4 = xs4[fq];
                acc = fmaf(x4.x, c4.x, acc);
                acc = fmaf(x4.y, c4.y, acc);
                acc = fmaf(x4.z, c4.z, acc);
                acc = fmaf(x4.w, c4.w, acc);
            }
            float v = fmaf(-2.f, acc, nxf + n_arr[tid]);
            vsh[tid] = v;
            keys[tid] = (((unsigned long long)__float_as_uint(v)) << 32) | (unsigned)tid;
        }
        __syncthreads();
        for (int st = 256; st; st >>= 1) {
            if (tid < st) {
                unsigned long long o = keys[tid + st];
                if (o < keys[tid]) keys[tid] = o;
            }
            __syncthreads();
        }
        int newj = (int)(keys[0] & 0xffffffffu);
        int oldj = oldj_sh;
        if (newj != oldj) {
            if (tid == 0) {
                out[OFF_ENC + (size_t)t * 512 + oldj] = 0.0f;
                out[OFF_ENC + (size_t)t * 512 + newj] = 1.0f;
                atomicSub(&counts[oldj], 1u);
                atomicAdd(&counts[newj], 1u);
                atomicAdd(vq_acc, (double)vsh[newj] - (double)vsh[oldj]);
            }
            if (tid < 128) {
                float4 cn = *(const float4*)(cw + (size_t)newj * DIM + tid * 4);
                *(float4*)&out[OFF_QW + (size_t)t * 512 + tid * 4] = cn;
            }
        }
        __syncthreads();
    }
}

// ---------------------------------------------------------------------------
// docu partials: 8 blocks; block b reduces j in [64b, 64b+64) into double
// partials per dim, one atomicAdd(double) per (block, dim) — 8 adders/addr.
__global__ __launch_bounds__(512)
void k_docu(const unsigned* __restrict__ counts, const float* __restrict__ cw,
            double* __restrict__ docu_d) {
    __shared__ float cnt[64];
    const int tid = threadIdx.x;
    const int j0 = blockIdx.x * 64;
    if (tid < 64) cnt[tid] = (float)counts[j0 + tid];
    __syncthreads();
    double a = 0.0;
    #pragma unroll 8
    for (int j = 0; j < 64; ++j)
        a += (double)cnt[j] * (double)cw[(size_t)(j0 + j) * DIM + tid];
    atomicAdd(&docu_d[tid], a);
}

// ---------------------------------------------------------------------------
// lts via MFMA on fp16 (512*c): one wave per 32x32 tile of the KxK Gram.
// Block 0 additionally converts docu_d -> out_docu (stream-ordered after
// k_docu). dd = n_i + n_j - 2*(acc/512^2) + 2e-6*(s_i - s_j) + 512e-12.
__global__ __launch_bounds__(256)
void k_ltsm(const float* __restrict__ n_arr, const float* __restrict__ s_arr,
            double* __restrict__ lts_acc, const double* __restrict__ docu_d,
            float* __restrict__ out_docu) {
    const int tid  = threadIdx.x;
    if (blockIdx.x == 0) {
        out_docu[tid]       = (float)(docu_d[tid]       * (1.0 / (double)N_TOK));
        out_docu[tid + 256] = (float)(docu_d[tid + 256] * (1.0 / (double)N_TOK));
    }
    const int lane = tid & 63;
    const int wv   = tid >> 6;
    const int hv   = lane >> 5;
    const int ln31 = lane & 31;
    const int tile = blockIdx.x * 4 + wv;   // 0..255
    const int ti = tile >> 4, tj = tile & 15;

    const f16x8* bt = (const f16x8*)g_B1;
    f32x16 acc = (f32x16)(0.0f);
    #pragma unroll
    for (int s = 0; s < 32; ++s) {
        f16x8 af = bt[((size_t)s * 2 + hv) * 512 + ti * 32 + ln31];
        f16x8 bf = bt[((size_t)s * 2 + hv) * 512 + tj * 32 + ln31];
        acc = __builtin_amdgcn_mfma_f32_32x32x16_f16(af, bf, acc, 0, 0, 0);
    }

    const int j = tj * 32 + ln31;
    const float nj = n_arr[j], sj = s_arr[j];
    const float EPS = 1e-6f;
    double lsum = 0.0;
    #pragma unroll
    for (int r = 0; r < 16; ++r) {
        int row = (r & 3) + ((r >> 2) << 3) + (hv << 2);
        int i = ti * 32 + row;
        float ddv = n_arr[i] + nj
                  + fmaf(-2.0f / 262144.0f, acc[r],
                         2.f * EPS * (s_arr[i] - sj) + 512.f * EPS * EPS);
        float dist = sqrtf(fmaxf(ddv, 0.f));
        lsum += (double)((i == j) ? dist : fmaxf(0.f, 1.f - dist));
    }
    for (int off = 32; off; off >>= 1) lsum += __shfl_down(lsum, off);
    if (lane == 0) atomicAdd(lts_acc, lsum);
}

// logits -> e = exp(logit + bias), per-block partial sums (uncontended)
__global__ void k_logexp(const float* __restrict__ docu, const float* __restrict__ q2w,
                         const float* __restrict__ q2b, float* __restrict__ evals,
                         double* __restrict__ parts) {
    __shared__ double esh[4];
    int wvi = threadIdx.x >> 6, lane = threadIdx.x & 63;
    int v = blockIdx.x * 4 + wvi;
    if (lane == 0) esh[wvi] = 0.0;
    if (v < VOCAB) {
        const float* wr = q2w + (size_t)v * DIM;
        float4 a = *(const float4*)(wr + lane*8);
        float4 b = *(const float4*)(wr + lane*8 + 4);
        float4 da = *(const float4*)(docu + lane*8);
        float4 db = *(const float4*)(docu + lane*8 + 4);
        float p = a.x*da.x + a.y*da.y + a.z*da.z + a.w*da.w
                + b.x*db.x + b.y*db.y + b.z*db.z + b.w*db.w;
        for (int off = 32; off; off >>= 1) p += __shfl_down(p, off);
        if (lane == 0) {
            float e = expf(p + q2b[v]);
            evals[v] = e;
            esh[wvi] = (double)e;
        }
    }
    __syncthreads();
    if (threadIdx.x == 0)
        parts[blockIdx.x] = esh[0] + esh[1] + esh[2] + esh[3];
}

__global__ void k_sumred(const double* __restrict__ parts, double* __restrict__ sumv) {
    __shared__ double red[256];
    int tid = threadIdx.x;
    double s = 0.0;
    for (int i = tid; i < NPARTS; i += 256) s += parts[i];
    red[tid] = s; __syncthreads();
    for (int st = 128; st; st >>= 1) {
        if (tid < st) red[tid] += red[tid + st];
        __syncthreads();
    }
    if (tid == 0) *sumv = red[0];
}

__global__ void k_final(const float* __restrict__ evals,
                        const double* __restrict__ sumv, const unsigned* __restrict__ binc,
                        const double* __restrict__ vq_acc, const double* __restrict__ lts_acc,
                        float* __restrict__ out) {
    int v = blockIdx.x * 256 + threadIdx.x;
    if (v < VOCAB) {
        float s = (float)(*sumv);
        float p = evals[v] / s;
        out[OFF_OUT + v] = logf(p + 1e-6f) * (float)binc[v];
    }
    if (v == 0) {
        out[OFF_VQ]  = (float)(1.25 * (*vq_acc) * (1.0 / 67108864.0));
        out[OFF_LTS] = (float)((*lts_acc) * (1.0 / 262144.0));
    }
}

// ---------------------------------------------------------------------------
extern "C" void kernel_launch(void* const* d_in, const int* in_sizes, int n_in,
                              void* d_out, int out_size, void* d_ws, size_t ws_size,
                              hipStream_t stream) {
    const int*   doc = (const int*)d_in[0];
    const float* emb = (const float*)d_in[1];
    const float* cw  = (const float*)d_in[2];
    const float* q2w = (const float*)d_in[3];
    const float* q2b = (const float*)d_in[4];
    float* out = (float*)d_out;
    char* ws = (char*)d_ws;

    unsigned* counts = (unsigned*)(ws + WS_COUNTS);
    double*   vq_acc = (double*)(ws + WS_VQ);
    double*   lts_acc= (double*)(ws + WS_LTS);
    double*   sumv   = (double*)(ws + WS_SUMV);
    unsigned* nflag  = (unsigned*)(ws + WS_NFLAG);
    float*    n_arr  = (float*)(ws + WS_NARR);
    float*    s_arr  = (float*)(ws + WS_SARR);
    unsigned* binc   = (unsigned*)(ws + WS_BINC);
    float*    evals  = (float*)(ws + WS_LOGITS);
    unsigned* flags  = (unsigned*)(ws + WS_FLAGS);
    double*   parts  = (double*)(ws + WS_PART);
    double*   docu_d = (double*)(ws + WS_DOCUD);

    _Float16* b1;  hipGetSymbolAddress((void**)&b1,  HIP_SYMBOL(g_B1));
    _Float16* a16; hipGetSymbolAddress((void**)&a16, HIP_SYMBOL(g_A16));
    float*    nw;  hipGetSymbolAddress((void**)&nw,  HIP_SYMBOL(g_NW));

    // scalars zeroed by k_nsprep block 0, docu_d by block 1, binc by k_prepa

    hipLaunchKernelGGL(k_nsprep, dim3(128),   dim3(256), 0, stream, cw, n_arr, s_arr,
                       b1, (uint4*)ws, (uint4*)(ws + WS_DOCUD));
    hipLaunchKernelGGL(k_prepa,  dim3(NPARTS), dim3(256), 0, stream, emb, a16, nw, binc);
    hipLaunchKernelGGL(k_main,   dim3(2048),  dim3(512), 0, stream, doc, cw, n_arr,
                       out, counts, binc, vq_acc, nflag, flags);
    hipLaunchKernelGGL(k_fixup,  dim3(2048),  dim3(512), 0, stream, doc, emb, cw, n_arr,
                       nw, nflag, flags, out, counts, vq_acc);
    hipLaunchKernelGGL(k_docu,   dim3(8),     dim3(512), 0, stream, counts, cw, docu_d);
    hipLaunchKernelGGL(k_ltsm,   dim3(64),    dim3(256), 0, stream, n_arr, s_arr, lts_acc,
                       docu_d, out + OFF_DOCU);
    hipLaunchKernelGGL(k_logexp, dim3(NPARTS), dim3(256), 0, stream,
                       out + OFF_DOCU, q2w, q2b, evals, parts);
    hipLaunchKernelGGL(k_sumred, dim3(1), dim3(256), 0, stream, parts, sumv);
    hipLaunchKernelGGL(k_final,  dim3((VOCAB + 255) / 256), dim3(256), 0, stream,
                       evals, sumv, binc, vq_acc, lts_acc, out);
}

// Round 18
// 367.350 us; speedup vs baseline: 1.2230x; 1.0115x over previous
//
#include <hip/hip_runtime.h>
#include <math.h>

#define N_TOK 131072
#define VOCAB 50257
#define DIM   512
#define K_CON 512
#define NPARTS 12565   // ceil(VOCAB/4)

// d_out layout (float32 elements)
#define OFF_ENC  ((size_t)0)
#define OFF_QW   ((size_t)67108864)
#define OFF_DOCU ((size_t)134217728)
#define OFF_OUT  ((size_t)134218240)
#define OFF_VQ   ((size_t)134268497)
#define OFF_LTS  ((size_t)134268498)

// ws layout (bytes)
#define WS_COUNTS 0        // 512 * u32
#define WS_VQ     2048     // double
#define WS_LTS    2056     // double
#define WS_SUMV   2072     // double
#define WS_NFLAG  2080     // u32
#define WS_NARR   4096     // 512 f32
#define WS_SARR   6144     // 512 f32
#define WS_BINC   8192     // VOCAB u32
#define WS_LOGITS 209920   // VOCAB f32 (holds exp(logit))
#define WS_FLAGS  411648   // FLAG_CAP u32  (ends 542720)
#define WS_PART   544768   // NPARTS double (ends 645288)
#define WS_DOCUD  645632   // 512 double (docu partial sums)
#define FLAG_CAP  32768

typedef __attribute__((ext_vector_type(4)))  float f32x4;
typedef __attribute__((ext_vector_type(8)))  _Float16 f16x8;
typedef __attribute__((ext_vector_type(16))) float f32x16;

// Codebook as fp16 of (512*c): frag [(s*2+hf)*512 + c] x f16x8. 512 KB.
// K-step tile s = 16 KB at byte offset s*16384 (first 8 KB hf=0, then hf=1).
__device__ _Float16 g_B1[32 * 2 * 512 * 8];
// Embedding table as fp16 (unscaled), row-major [VOCAB][512]. ~51.5 MB.
__device__ _Float16 g_A16[(size_t)VOCAB * DIM];
// Per-vocab-row |x|^2 (double-accumulated, rounded to f32).
__device__ float g_NW[VOCAB];

__device__ inline void gload16(const void* g, void* l) {
    __builtin_amdgcn_global_load_lds(
        (const __attribute__((address_space(1))) unsigned int*)g,
        (__attribute__((address_space(3))) unsigned int*)l, 16, 0, 0);
}

// ---------------------------------------------------------------------------
// merged prep: emb -> fp16 table + |x|^2 + binc zero (all blocks);
// blocks 0..127 also: codebook n/s arrays + fp16 (512*c) staging layout;
// blocks 0/1: ws scratch zeroing.
__global__ void k_prep(const float* __restrict__ emb, const float* __restrict__ cw,
                       _Float16* __restrict__ a16, float* __restrict__ nw,
                       unsigned* __restrict__ binc,
                       float* __restrict__ n_arr, float* __restrict__ s_arr,
                       _Float16* __restrict__ b1,
                       uint4* __restrict__ wz, uint4* __restrict__ wzd) {
    const int wv = threadIdx.x >> 6, lane = threadIdx.x & 63;
    if (blockIdx.x == 0) {
        uint4 z; z.x = 0u; z.y = 0u; z.z = 0u; z.w = 0u;
        wz[threadIdx.x] = z;          // 4 KB scalar region
    } else if (blockIdx.x == 1) {
        uint4 z; z.x = 0u; z.y = 0u; z.z = 0u; z.w = 0u;
        wzd[threadIdx.x] = z;         // 4 KB docu partial region
    }
    // vocab rows
    {
        int r = blockIdx.x * 4 + wv;
        if (r < VOCAB) {
            const float* row = emb + (size_t)r * DIM;
            float4 a = *(const float4*)(row + lane * 8);
            float4 b = *(const float4*)(row + lane * 8 + 4);
            float v[8] = {a.x,a.y,a.z,a.w,b.x,b.y,b.z,b.w};
            f16x8 h;
            double na = 0.0;
            #pragma unroll
            for (int e = 0; e < 8; ++e) { h[e] = (_Float16)v[e]; na += (double)v[e]*v[e]; }
            *(f16x8*)&a16[(size_t)r * DIM + lane * 8] = h;
            for (int off = 32; off; off >>= 1) na += __shfl_down(na, off);
            if (lane == 0) { nw[r] = (float)na; binc[r] = 0u; }
        }
    }
    // codebook rows (blocks 0..127)
    if (blockIdx.x < 128) {
        int r = blockIdx.x * 4 + wv;
        const float* row = cw + (size_t)r * DIM;
        {
            float4 a = *(const float4*)(row + lane * 8);
            float4 b = *(const float4*)(row + lane * 8 + 4);
            float v[8] = {a.x,a.y,a.z,a.w,b.x,b.y,b.z,b.w};
            double na = 0.0, sa = 0.0;
            #pragma unroll
            for (int e = 0; e < 8; ++e) { na += (double)v[e]*v[e]; sa += (double)v[e]; }
            for (int off = 32; off; off >>= 1) {
                na += __shfl_down(na, off);
                sa += __shfl_down(sa, off);
            }
            if (lane == 0) { n_arr[r] = (float)na; s_arr[r] = (float)sa; }
        }
        {
            int s = lane >> 1, hf = lane & 1;
            const float* p = row + s * 16 + hf * 8;
            float4 xa = *(const float4*)p;
            float4 xb = *(const float4*)(p + 4);
            float xf[8] = {xa.x,xa.y,xa.z,xa.w,xb.x,xb.y,xb.z,xb.w};
            f16x8 h8;
            #pragma unroll
            for (int e = 0; e < 8; ++e) h8[e] = (_Float16)(xf[e] * 512.0f);
            *(f16x8*)&b1[(((size_t)s * 2 + hf) * 512 + r) * 8] = h8;
        }
    }
}

// ---------------------------------------------------------------------------
// Main: fp16 single-term MFMA distance GEMM. 512 threads = 8 waves (2
// token-groups x 4 concept-quarters). B in 4 x 16 KB LDS ring (BK=16, 32
// phases), counted-vmcnt pipeline: stage(p+3) issued at phase p; boundary
// entering p waits vmcnt(6) (tail: 3, 0) -> s_barrier. 2 blocks/CU.
__global__ __launch_bounds__(512, 4)
void k_main(const int* __restrict__ doc, const float* __restrict__ cw,
            const float* __restrict__ n_arr,
            float* __restrict__ out, unsigned* __restrict__ counts,
            unsigned* __restrict__ binc,
            double* __restrict__ vq_acc, unsigned* __restrict__ nflag,
            unsigned* __restrict__ flag_list) {
    __shared__ f16x8 bsh[4][1024];      // 64 KB ring of K-step tiles
    __shared__ float nsl[512];
    __shared__ float nxs[64];
    __shared__ uint4 redv[8][64];       // 8 KB
    __shared__ int docs[64];
    __shared__ int idxs[64];
    __shared__ double dred[512];        // 4 KB

    const int tid   = threadIdx.x;
    const int n0    = blockIdx.x * 64;
    const int lane  = tid & 63;
    const int wv    = tid >> 6;
    const int wm    = wv >> 2;          // token group 0/1
    const int wq    = wv & 3;           // concept quarter
    const int hv    = lane >> 5;
    const int ln31  = lane & 31;
    const int cbase = wq * 128 + ln31;

    if (tid < 64) docs[tid] = doc[n0 + tid];
    nsl[tid] = n_arr[tid];
    __syncthreads();

#define STAGE16(P, DST)                                                       \
    {                                                                         \
        const char* srcb = (const char*)g_B1 + (size_t)(P) * 16384;           \
        char* dstb = (char*)(DST);                                            \
        gload16(srcb + tid * 16, dstb + tid * 16);                            \
        gload16(srcb + 8192 + tid * 16, dstb + 8192 + tid * 16);              \
    }

    const char* aptr = (const char*)(g_A16 + (size_t)docs[wm * 32 + ln31] * DIM);

    // prologue: stage steps 0..2; A(0..2) to regs; nx from table
    STAGE16(0, bsh[0]);
    STAGE16(1, bsh[1]);
    STAGE16(2, bsh[2]);
    f16x8 x0 = *(const f16x8*)(aptr + (hv * 8) * 2);
    f16x8 x1 = *(const f16x8*)(aptr + (16 + hv * 8) * 2);
    f16x8 x2 = *(const f16x8*)(aptr + (32 + hv * 8) * 2);
    if (tid < 64) nxs[tid] = g_NW[docs[tid]];
    __syncthreads();   // one-time full drain: stages 0-2 + A + nxs

    f32x16 acc[4];
    #pragma unroll
    for (int n = 0; n < 4; ++n) acc[n] = (f32x16)(0.0f);

    #pragma unroll
    for (int p = 0; p < 32; ++p) {
        if (p >= 1) {
            __builtin_amdgcn_sched_barrier(0);
            if (p <= 29)      asm volatile("s_waitcnt vmcnt(6)" ::: "memory");
            else if (p == 30) asm volatile("s_waitcnt vmcnt(3)" ::: "memory");
            else              asm volatile("s_waitcnt vmcnt(0)" ::: "memory");
            __builtin_amdgcn_sched_barrier(0);
            __builtin_amdgcn_s_barrier();
            __builtin_amdgcn_sched_barrier(0);
        }
        f16x8 na = x2;
        if (p + 3 < 32) {
            na = *(const f16x8*)(aptr + ((p + 3) * 16 + hv * 8) * 2);
            __builtin_amdgcn_sched_barrier(0);
            STAGE16(p + 3, bsh[(p + 3) & 3]);
            __builtin_amdgcn_sched_barrier(0);
        }
        const f16x8* bb = bsh[p & 3];
        #pragma unroll
        for (int n = 0; n < 4; ++n) {
            f16x8 b = bb[hv * 512 + cbase + n * 32];
            acc[n] = __builtin_amdgcn_mfma_f32_32x32x16_f16(x0, b, acc[n], 0, 0, 0);
        }
        x0 = x1; x1 = x2; x2 = na;
    }
#undef STAGE16
    __syncthreads();   // K-loop done

    float nsv[4];
    #pragma unroll
    for (int n = 0; n < 4; ++n) nsv[n] = nsl[cbase + n * 32];

    // per-row argmin + second best; C/D: col=lane&31, row=(r&3)+8*(r>>2)+4*hv
    // acc holds S = x_h . (512 c)_h ; d = fmaf(-2^-8, S, nx+nc)
    #pragma unroll
    for (int r = 0; r < 16; ++r) {
        int tt = (r & 3) + ((r >> 2) << 3) + (hv << 2);   // 0..31 within wm
        float nxr = nxs[wm * 32 + tt];
        float v1 = INFINITY, v2 = INFINITY; int j1 = 0x7fffffff;
        #pragma unroll
        for (int n = 0; n < 4; ++n) {
            float d = fmaf(-0.00390625f, acc[n][r], nxr + nsv[n]);
            int jj = cbase + n * 32;
            if (d < v1) { v2 = v1; v1 = d; j1 = jj; }
            else if (d < v2) { v2 = d; }
        }
        #pragma unroll
        for (int off = 1; off < 32; off <<= 1) {
            float ov1 = __shfl_xor(v1, off);
            int   oj1 = __shfl_xor(j1, off);
            float ov2 = __shfl_xor(v2, off);
            v2 = fminf(fminf(v2, ov2), fmaxf(v1, ov1));
            bool take = (ov1 < v1) || (ov1 == v1 && oj1 < j1);
            if (take) { v1 = ov1; j1 = oj1; }
        }
        if (ln31 == 0)
            redv[wv][wm * 32 + tt] = make_uint4(__float_as_uint(v1), (unsigned)j1,
                                                __float_as_uint(v2), 0u);
    }
    __syncthreads();
    double myv1 = 0.0;
    if (tid < 64) {
        int g = tid >> 5;   // token group
        uint4 a = redv[g * 4][tid];
        float v1 = __uint_as_float(a.x), v2 = __uint_as_float(a.z);
        int j1 = (int)a.y;
        #pragma unroll
        for (int w = 1; w < 4; ++w) {
            uint4 b = redv[g * 4 + w][tid];
            float wv1 = __uint_as_float(b.x), wv2 = __uint_as_float(b.z);
            v2 = fminf(fminf(v2, wv2), fmaxf(v1, wv1));
            bool take = (wv1 < v1) || (wv1 == v1 && (int)b.y < j1);
            if (take) { v1 = wv1; j1 = (int)b.y; }
        }
        idxs[tid] = j1;
        atomicAdd(&counts[j1], 1u);
        atomicAdd(&binc[docs[tid]], 1u);
        myv1 = (double)v1;
        if (v2 - v1 <= 2e-6f) {           // ~8 sigma of fp16-path noise
            unsigned pq = atomicAdd(nflag, 1u);
            if (pq < FLAG_CAP) flag_list[pq] = (unsigned)(n0 + tid);
        }
    }
    dred[tid] = myv1;
    __syncthreads();

    // encodings: one-hot rows (nontemporal streaming output; pure stores)
    for (int lin = tid; lin < 8192; lin += 512) {
        int t = lin >> 7, f4 = lin & 127;
        int idx = idxs[t];
        int b4 = f4 << 2;
        f32x4 v;
        v.x = (idx == b4)     ? 1.f : 0.f;
        v.y = (idx == b4 + 1) ? 1.f : 0.f;
        v.z = (idx == b4 + 2) ? 1.f : 0.f;
        v.w = (idx == b4 + 3) ? 1.f : 0.f;
        __builtin_nontemporal_store(v,
            (f32x4*)(out + OFF_ENC + ((size_t)(n0 + t) << 9) + (size_t)b4));
    }
    // quantized_words = codebook rows
    for (int lin = tid; lin < 8192; lin += 512) {
        int t = lin >> 7, f4 = lin & 127;
        f32x4 c4 = *(const f32x4*)(cw + (size_t)idxs[t] * DIM + (f4 << 2));
        __builtin_nontemporal_store(c4,
            (f32x4*)(out + OFF_QW + ((size_t)(n0 + t) << 9) + (size_t)(f4 << 2)));
    }
    // vq partial reduce (flagged tokens patched exactly by k_fixup)
    for (int st = 256; st; st >>= 1) {
        if (tid < st) dred[tid] += dred[tid + st];
        __syncthreads();
    }
    if (tid == 0) atomicAdd(vq_acc, dred[0]);
}

// ---------------------------------------------------------------------------
// Exact fp32 recompute for flagged near-tie tokens (vectorized, grid-stride).
__global__ __launch_bounds__(512)
void k_fixup(const int* __restrict__ doc, const float* __restrict__ emb,
             const float* __restrict__ cw, const float* __restrict__ n_arr,
             const float* __restrict__ nw,
             const unsigned* __restrict__ nflag, const unsigned* __restrict__ flag_list,
             float* __restrict__ out, unsigned* __restrict__ counts,
             double* __restrict__ vq_acc) {
    __shared__ float4 xs4[128];
    __shared__ int oldj_sh;
    __shared__ float vsh[512];
    __shared__ unsigned long long keys[512];

    const int tid = threadIdx.x;
    unsigned nf = *nflag;
    if (nf > FLAG_CAP) nf = FLAG_CAP;

    for (unsigned f = blockIdx.x; f < nf; f += gridDim.x) {
        int t = (int)flag_list[f];
        int dc = doc[t];
        float nxf = nw[dc];
        if (tid < 128)
            xs4[tid] = *(const float4*)(emb + (size_t)dc * DIM + tid * 4);
        if (tid == 0) oldj_sh = -1;
        __syncthreads();
        {
            float e = out[OFF_ENC + (size_t)t * 512 + tid];
            if (e == 1.0f) oldj_sh = tid;
        }
        {
            const float4* cr = (const float4*)(cw + (size_t)tid * DIM);
            float acc = 0.f;
            #pragma unroll 8
            for (int fq = 0; fq < 128; ++fq) {
                float4 c4 = cr[fq], x4 = xs4[fq];
                acc = fmaf(x4.x, c4.x, acc);
                acc = fmaf(x4.y, c4.y, acc);
                acc = fmaf(x4.z, c4.z, acc);
                acc = fmaf(x4.w, c4.w, acc);
            }
            float v = fmaf(-2.f, acc, nxf + n_arr[tid]);
            vsh[tid] = v;
            keys[tid] = (((unsigned long long)__float_as_uint(v)) << 32) | (unsigned)tid;
        }
        __syncthreads();
        for (int st = 256; st; st >>= 1) {
            if (tid < st) {
                unsigned long long o = keys[tid + st];
                if (o < keys[tid]) keys[tid] = o;
            }
            __syncthreads();
        }
        int newj = (int)(keys[0] & 0xffffffffu);
        int oldj = oldj_sh;
        if (newj != oldj) {
            if (tid == 0) {
                out[OFF_ENC + (size_t)t * 512 + oldj] = 0.0f;
                out[OFF_ENC + (size_t)t * 512 + newj] = 1.0f;
                atomicSub(&counts[oldj], 1u);
                atomicAdd(&counts[newj], 1u);
                atomicAdd(vq_acc, (double)vsh[newj] - (double)vsh[oldj]);
            }
            if (tid < 128) {
                float4 cn = *(const float4*)(cw + (size_t)newj * DIM + tid * 4);
                *(float4*)&out[OFF_QW + (size_t)t * 512 + tid * 4] = cn;
            }
        }
        __syncthreads();
    }
}

// ---------------------------------------------------------------------------
// docu partials: 8 blocks; block b reduces j in [64b, 64b+64) into double
// partials per dim, one atomicAdd(double) per (block, dim) — 8 adders/addr.
__global__ __launch_bounds__(512)
void k_docu(const unsigned* __restrict__ counts, const float* __restrict__ cw,
            double* __restrict__ docu_d) {
    __shared__ float cnt[64];
    const int tid = threadIdx.x;
    const int j0 = blockIdx.x * 64;
    if (tid < 64) cnt[tid] = (float)counts[j0 + tid];
    __syncthreads();
    double a = 0.0;
    #pragma unroll 8
    for (int j = 0; j < 64; ++j)
        a += (double)cnt[j] * (double)cw[(size_t)(j0 + j) * DIM + tid];
    atomicAdd(&docu_d[tid], a);
}

// ---------------------------------------------------------------------------
// lts via MFMA on fp16 (512*c): one wave per 32x32 tile of the KxK Gram.
// Block 0 additionally converts docu_d -> out_docu (stream-ordered after
// k_docu). dd = n_i + n_j - 2*(acc/512^2) + 2e-6*(s_i - s_j) + 512e-12.
__global__ __launch_bounds__(256)
void k_ltsm(const float* __restrict__ n_arr, const float* __restrict__ s_arr,
            double* __restrict__ lts_acc, const double* __restrict__ docu_d,
            float* __restrict__ out_docu) {
    const int tid  = threadIdx.x;
    if (blockIdx.x == 0) {
        out_docu[tid]       = (float)(docu_d[tid]       * (1.0 / (double)N_TOK));
        out_docu[tid + 256] = (float)(docu_d[tid + 256] * (1.0 / (double)N_TOK));
    }
    const int lane = tid & 63;
    const int wv   = tid >> 6;
    const int hv   = lane >> 5;
    const int ln31 = lane & 31;
    const int tile = blockIdx.x * 4 + wv;   // 0..255
    const int ti = tile >> 4, tj = tile & 15;

    const f16x8* bt = (const f16x8*)g_B1;
    f32x16 acc = (f32x16)(0.0f);
    #pragma unroll
    for (int s = 0; s < 32; ++s) {
        f16x8 af = bt[((size_t)s * 2 + hv) * 512 + ti * 32 + ln31];
        f16x8 bf = bt[((size_t)s * 2 + hv) * 512 + tj * 32 + ln31];
        acc = __builtin_amdgcn_mfma_f32_32x32x16_f16(af, bf, acc, 0, 0, 0);
    }

    const int j = tj * 32 + ln31;
    const float nj = n_arr[j], sj = s_arr[j];
    const float EPS = 1e-6f;
    double lsum = 0.0;
    #pragma unroll
    for (int r = 0; r < 16; ++r) {
        int row = (r & 3) + ((r >> 2) << 3) + (hv << 2);
        int i = ti * 32 + row;
        float ddv = n_arr[i] + nj
                  + fmaf(-2.0f / 262144.0f, acc[r],
                         2.f * EPS * (s_arr[i] - sj) + 512.f * EPS * EPS);
        float dist = sqrtf(fmaxf(ddv, 0.f));
        lsum += (double)((i == j) ? dist : fmaxf(0.f, 1.f - dist));
    }
    for (int off = 32; off; off >>= 1) lsum += __shfl_down(lsum, off);
    if (lane == 0) atomicAdd(lts_acc, lsum);
}

// logits -> e = exp(logit + bias), per-block partial sums (uncontended)
__global__ void k_logexp(const float* __restrict__ docu, const float* __restrict__ q2w,
                         const float* __restrict__ q2b, float* __restrict__ evals,
                         double* __restrict__ parts) {
    __shared__ double esh[4];
    int wvi = threadIdx.x >> 6, lane = threadIdx.x & 63;
    int v = blockIdx.x * 4 + wvi;
    if (lane == 0) esh[wvi] = 0.0;
    if (v < VOCAB) {
        const float* wr = q2w + (size_t)v * DIM;
        float4 a = *(const float4*)(wr + lane*8);
        float4 b = *(const float4*)(wr + lane*8 + 4);
        float4 da = *(const float4*)(docu + lane*8);
        float4 db = *(const float4*)(docu + lane*8 + 4);
        float p = a.x*da.x + a.y*da.y + a.z*da.z + a.w*da.w
                + b.x*db.x + b.y*db.y + b.z*db.z + b.w*db.w;
        for (int off = 32; off; off >>= 1) p += __shfl_down(p, off);
        if (lane == 0) {
            float e = expf(p + q2b[v]);
            evals[v] = e;
            esh[wvi] = (double)e;
        }
    }
    __syncthreads();
    if (threadIdx.x == 0)
        parts[blockIdx.x] = esh[0] + esh[1] + esh[2] + esh[3];
}

__global__ void k_sumred(const double* __restrict__ parts, double* __restrict__ sumv) {
    __shared__ double red[256];
    int tid = threadIdx.x;
    double s = 0.0;
    for (int i = tid; i < NPARTS; i += 256) s += parts[i];
    red[tid] = s; __syncthreads();
    for (int st = 128; st; st >>= 1) {
        if (tid < st) red[tid] += red[tid + st];
        __syncthreads();
    }
    if (tid == 0) *sumv = red[0];
}

__global__ void k_final(const float* __restrict__ evals,
                        const double* __restrict__ sumv, const unsigned* __restrict__ binc,
                        const double* __restrict__ vq_acc, const double* __restrict__ lts_acc,
                        float* __restrict__ out) {
    int v = blockIdx.x * 256 + threadIdx.x;
    if (v < VOCAB) {
        float s = (float)(*sumv);
        float p = evals[v] / s;
        out[OFF_OUT + v] = logf(p + 1e-6f) * (float)binc[v];
    }
    if (v == 0) {
        out[OFF_VQ]  = (float)(1.25 * (*vq_acc) * (1.0 / 67108864.0));
        out[OFF_LTS] = (float)((*lts_acc) * (1.0 / 262144.0));
    }
}

// ---------------------------------------------------------------------------
extern "C" void kernel_launch(void* const* d_in, const int* in_sizes, int n_in,
                              void* d_out, int out_size, void* d_ws, size_t ws_size,
                              hipStream_t stream) {
    const int*   doc = (const int*)d_in[0];
    const float* emb = (const float*)d_in[1];
    const float* cw  = (const float*)d_in[2];
    const float* q2w = (const float*)d_in[3];
    const float* q2b = (const float*)d_in[4];
    float* out = (float*)d_out;
    char* ws = (char*)d_ws;

    unsigned* counts = (unsigned*)(ws + WS_COUNTS);
    double*   vq_acc = (double*)(ws + WS_VQ);
    double*   lts_acc= (double*)(ws + WS_LTS);
    double*   sumv   = (double*)(ws + WS_SUMV);
    unsigned* nflag  = (unsigned*)(ws + WS_NFLAG);
    float*    n_arr  = (float*)(ws + WS_NARR);
    float*    s_arr  = (float*)(ws + WS_SARR);
    unsigned* binc   = (unsigned*)(ws + WS_BINC);
    float*    evals  = (float*)(ws + WS_LOGITS);
    unsigned* flags  = (unsigned*)(ws + WS_FLAGS);
    double*   parts  = (double*)(ws + WS_PART);
    double*   docu_d = (double*)(ws + WS_DOCUD);

    _Float16* b1;  hipGetSymbolAddress((void**)&b1,  HIP_SYMBOL(g_B1));
    _Float16* a16; hipGetSymbolAddress((void**)&a16, HIP_SYMBOL(g_A16));
    float*    nw;  hipGetSymbolAddress((void**)&nw,  HIP_SYMBOL(g_NW));

    // scalars zeroed by k_prep blocks 0/1, binc by k_prep per-row

    hipLaunchKernelGGL(k_prep,   dim3(NPARTS), dim3(256), 0, stream, emb, cw, a16, nw,
                       binc, n_arr, s_arr, b1, (uint4*)ws, (uint4*)(ws + WS_DOCUD));
    hipLaunchKernelGGL(k_main,   dim3(2048),  dim3(512), 0, stream, doc, cw, n_arr,
                       out, counts, binc, vq_acc, nflag, flags);
    hipLaunchKernelGGL(k_fixup,  dim3(2048),  dim3(512), 0, stream, doc, emb, cw, n_arr,
                       nw, nflag, flags, out, counts, vq_acc);
    hipLaunchKernelGGL(k_docu,   dim3(8),     dim3(512), 0, stream, counts, cw, docu_d);
    hipLaunchKernelGGL(k_ltsm,   dim3(64),    dim3(256), 0, stream, n_arr, s_arr, lts_acc,
                       docu_d, out + OFF_DOCU);
    hipLaunchKernelGGL(k_logexp, dim3(NPARTS), dim3(256), 0, stream,
                       out + OFF_DOCU, q2w, q2b, evals, parts);
    hipLaunchKernelGGL(k_sumred, dim3(1), dim3(256), 0, stream, parts, sumv);
    hipLaunchKernelGGL(k_final,  dim3((VOCAB + 255) / 256), dim3(256), 0, stream,
                       evals, sumv, binc, vq_acc, lts_acc, out);
}